// Round 1
// baseline (1075.763 us; speedup 1.0000x reference)
//
#include <hip/hip_runtime.h>
#include <math.h>

#define N_PTS 8192
#define D 128
#define KNN 16
#define NCHUNK 4
#define CHUNK (N_PTS / NCHUNK)   // 2048
#define QPB 64                    // queries per block (1 wave)

// ---------------------------------------------------------------------------
// Kernel 1: partial KNN. Each block: 64 queries x one candidate chunk of 2048.
// grid (256, 4), block 64. Output: per-(query,chunk) sorted top-16 (dist, idx).
// ---------------------------------------------------------------------------
__global__ __launch_bounds__(QPB) void knn_partial(const float* __restrict__ xyz,
                                                   float* __restrict__ pdist,
                                                   int* __restrict__ pidx) {
    __shared__ float4 tile[CHUNK];   // 32 KB: x,y,z,|x|^2
    const int qg = blockIdx.x;       // 0..255
    const int chunk = blockIdx.y;    // 0..3
    const int g = qg * QPB + threadIdx.x;   // global query id 0..16383
    const int b = g >> 13;
    const int n = g & (N_PTS - 1);
    const float* X = xyz + (size_t)b * N_PTS * 3;

    const float qx = X[n * 3 + 0];
    const float qy = X[n * 3 + 1];
    const float qz = X[n * 3 + 2];
    const float qn = qx * qx + qy * qy + qz * qz;

    const int cbase = chunk * CHUNK;
    for (int i = threadIdx.x; i < CHUNK; i += QPB) {
        const float x = X[(cbase + i) * 3 + 0];
        const float y = X[(cbase + i) * 3 + 1];
        const float z = X[(cbase + i) * 3 + 2];
        tile[i] = make_float4(x, y, z, x * x + y * y + z * z);
    }
    __syncthreads();

    float dist[KNN];
    int idx[KNN];
#pragma unroll
    for (int s = 0; s < KNN; ++s) { dist[s] = 1e30f; idx[s] = 0; }

#pragma unroll 4
    for (int j = 0; j < CHUNK; ++j) {
        const float4 c = tile[j];
        const float dot = qx * c.x + qy * c.y + qz * c.z;
        const float d = fmaf(-2.f, dot, qn + c.w);   // matches ref formula
        if (d < dist[KNN - 1]) {
            dist[KNN - 1] = d;
            idx[KNN - 1] = cbase + j;
#pragma unroll
            for (int s = KNN - 1; s > 0; --s) {
                if (dist[s] < dist[s - 1]) {
                    const float td = dist[s]; dist[s] = dist[s - 1]; dist[s - 1] = td;
                    const int ti = idx[s]; idx[s] = idx[s - 1]; idx[s - 1] = ti;
                }
            }
        }
    }

    const int ob = (g * NCHUNK + chunk) * KNN;
#pragma unroll
    for (int s = 0; s < KNN; ++s) {
        pdist[ob + s] = dist[s];
        pidx[ob + s] = idx[s] + b * N_PTS;   // absolute point id
    }
}

// ---------------------------------------------------------------------------
// Kernel 2: merge 4 sorted partial lists -> final top-16 indices per query.
// grid 64, block 256. Chunk-major scan preserves ref tie-breaking (lower idx).
// ---------------------------------------------------------------------------
__global__ __launch_bounds__(256) void knn_merge(const float* __restrict__ pdist,
                                                 const int* __restrict__ pidx,
                                                 int* __restrict__ knn_out) {
    const int g = blockIdx.x * 256 + threadIdx.x;   // 0..16383
    float dist[KNN];
    int idx[KNN];
#pragma unroll
    for (int s = 0; s < KNN; ++s) { dist[s] = 1e30f; idx[s] = 0; }

    const int base = g * NCHUNK * KNN;
    for (int t = 0; t < NCHUNK * KNN; ++t) {
        const float d = pdist[base + t];
        const int id = pidx[base + t];
        if (d < dist[KNN - 1]) {
            dist[KNN - 1] = d;
            idx[KNN - 1] = id;
#pragma unroll
            for (int s = KNN - 1; s > 0; --s) {
                if (dist[s] < dist[s - 1]) {
                    const float td = dist[s]; dist[s] = dist[s - 1]; dist[s - 1] = td;
                    const int ti = idx[s]; idx[s] = idx[s - 1]; idx[s - 1] = ti;
                }
            }
        }
    }
#pragma unroll
    for (int s = 0; s < KNN; ++s) knn_out[g * KNN + s] = idx[s];
}

// ---------------------------------------------------------------------------
// Kernel 3: q/k/v projections. Block = 64 rows x all 3 matrices.
// grid 256, block 256. Feature tile in LDS; weights stream from L2 (coalesced).
// ---------------------------------------------------------------------------
__global__ __launch_bounds__(256) void qkv_kernel(const float* __restrict__ feat,
                                                  const float* __restrict__ wq, const float* __restrict__ bq,
                                                  const float* __restrict__ wk, const float* __restrict__ bk,
                                                  const float* __restrict__ wv, const float* __restrict__ bv,
                                                  float* __restrict__ qbuf, float* __restrict__ kbuf,
                                                  float* __restrict__ vbuf) {
    __shared__ float ftile[64][D];   // 32 KB
    const int r0 = blockIdx.x * 64;

    const float* src = feat + (size_t)r0 * D;
    for (int i = threadIdx.x; i < 64 * D / 4; i += 256) {
        ((float4*)&ftile[0][0])[i] = ((const float4*)src)[i];
    }
    __syncthreads();

    const int col = threadIdx.x & (D - 1);
    const int rbase = (threadIdx.x >> 7) * 32;

    float accq[32], acck[32], accv[32];
    const float bqv = bq[col], bkv = bk[col], bvv = bv[col];
#pragma unroll
    for (int r = 0; r < 32; ++r) { accq[r] = bqv; acck[r] = bkv; accv[r] = bvv; }

    for (int i = 0; i < D; i += 4) {
        const float wq0 = wq[(i + 0) * D + col], wq1 = wq[(i + 1) * D + col];
        const float wq2 = wq[(i + 2) * D + col], wq3 = wq[(i + 3) * D + col];
        const float wk0 = wk[(i + 0) * D + col], wk1 = wk[(i + 1) * D + col];
        const float wk2 = wk[(i + 2) * D + col], wk3 = wk[(i + 3) * D + col];
        const float wv0 = wv[(i + 0) * D + col], wv1 = wv[(i + 1) * D + col];
        const float wv2 = wv[(i + 2) * D + col], wv3 = wv[(i + 3) * D + col];
#pragma unroll
        for (int r = 0; r < 32; ++r) {
            const float4 f = *(const float4*)&ftile[rbase + r][i];
            accq[r] = fmaf(f.x, wq0, accq[r]); accq[r] = fmaf(f.y, wq1, accq[r]);
            accq[r] = fmaf(f.z, wq2, accq[r]); accq[r] = fmaf(f.w, wq3, accq[r]);
            acck[r] = fmaf(f.x, wk0, acck[r]); acck[r] = fmaf(f.y, wk1, acck[r]);
            acck[r] = fmaf(f.z, wk2, acck[r]); acck[r] = fmaf(f.w, wk3, acck[r]);
            accv[r] = fmaf(f.x, wv0, accv[r]); accv[r] = fmaf(f.y, wv1, accv[r]);
            accv[r] = fmaf(f.z, wv2, accv[r]); accv[r] = fmaf(f.w, wv3, accv[r]);
        }
    }
#pragma unroll
    for (int r = 0; r < 32; ++r) {
        const size_t o = (size_t)(r0 + rbase + r) * D + col;
        qbuf[o] = accq[r]; kbuf[o] = acck[r]; vbuf[o] = accv[r];
    }
}

// ---------------------------------------------------------------------------
// Kernel 4: fused point-transformer. Block = 1 point, 128 threads (= channel).
// Softmax over neighbor axis is thread-local (16 regs per thread).
// ---------------------------------------------------------------------------
__global__ __launch_bounds__(128) void fused_kernel(const float* __restrict__ xyz,
                                                    const float* __restrict__ qbuf,
                                                    const float* __restrict__ kbuf,
                                                    const float* __restrict__ vbuf,
                                                    const int* __restrict__ knn_in,
                                                    const float* __restrict__ pw1, const float* __restrict__ pb1,
                                                    const float* __restrict__ pw2, const float* __restrict__ pb2,
                                                    const float* __restrict__ aw1, const float* __restrict__ ab1,
                                                    const float* __restrict__ aw2, const float* __restrict__ ab2,
                                                    float* __restrict__ out) {
    __shared__ float bufA[KNN][D];   // 8 KB (h1, then h2)
    __shared__ float bufB[KNN][D];   // 8 KB (attn_in)
    __shared__ float diff[KNN][4];
    __shared__ int nbr[KNN];

    const int n = blockIdx.x;   // absolute point 0..16383
    const int c = threadIdx.x;  // channel

    if (c < KNN) {
        const int id = knn_in[n * KNN + c];
        nbr[c] = id;
        diff[c][0] = xyz[n * 3 + 0] - xyz[id * 3 + 0];
        diff[c][1] = xyz[n * 3 + 1] - xyz[id * 3 + 1];
        diff[c][2] = xyz[n * 3 + 2] - xyz[id * 3 + 2];
    }
    __syncthreads();

    // Phase A: h1 = relu(pos_diff @ pw1 + pb1) -> bufA
    {
        const float w0 = pw1[0 * D + c], w1 = pw1[1 * D + c], w2 = pw1[2 * D + c];
        const float b1 = pb1[c];
#pragma unroll
        for (int k = 0; k < KNN; ++k) {
            float h = b1;
            h = fmaf(diff[k][0], w0, h);
            h = fmaf(diff[k][1], w1, h);
            h = fmaf(diff[k][2], w2, h);
            bufA[k][c] = fmaxf(h, 0.f);
        }
    }
    __syncthreads();

    // Phase B: delta = bufA @ pw2 + pb2 (registers)
    float delta[KNN];
    {
        const float b2 = pb2[c];
#pragma unroll
        for (int k = 0; k < KNN; ++k) delta[k] = b2;
        for (int j = 0; j < D; j += 4) {
            const float w0 = pw2[(j + 0) * D + c], w1 = pw2[(j + 1) * D + c];
            const float w2 = pw2[(j + 2) * D + c], w3 = pw2[(j + 3) * D + c];
#pragma unroll
            for (int k = 0; k < KNN; ++k) {
                const float4 h = *(const float4*)&bufA[k][j];
                delta[k] = fmaf(h.x, w0, delta[k]);
                delta[k] = fmaf(h.y, w1, delta[k]);
                delta[k] = fmaf(h.z, w2, delta[k]);
                delta[k] = fmaf(h.w, w3, delta[k]);
            }
        }
    }

    // Phase C: attn_in = q - k_g + delta -> bufB
    {
        const float qv = qbuf[(size_t)n * D + c];
#pragma unroll
        for (int k = 0; k < KNN; ++k) {
            const float kg = kbuf[(size_t)nbr[k] * D + c];
            bufB[k][c] = qv - kg + delta[k];
        }
    }
    __syncthreads();   // bufB ready; everyone done reading bufA

    // Phase D: h2 = relu(bufB @ aw1 + ab1) -> bufA
    float acc[KNN];
    {
        const float b1 = ab1[c];
#pragma unroll
        for (int k = 0; k < KNN; ++k) acc[k] = b1;
        for (int j = 0; j < D; j += 4) {
            const float w0 = aw1[(j + 0) * D + c], w1 = aw1[(j + 1) * D + c];
            const float w2 = aw1[(j + 2) * D + c], w3 = aw1[(j + 3) * D + c];
#pragma unroll
            for (int k = 0; k < KNN; ++k) {
                const float4 h = *(const float4*)&bufB[k][j];
                acc[k] = fmaf(h.x, w0, acc[k]);
                acc[k] = fmaf(h.y, w1, acc[k]);
                acc[k] = fmaf(h.z, w2, acc[k]);
                acc[k] = fmaf(h.w, w3, acc[k]);
            }
        }
#pragma unroll
        for (int k = 0; k < KNN; ++k) bufA[k][c] = fmaxf(acc[k], 0.f);
    }
    __syncthreads();   // bufA(h2) ready

    // Phase E: attn = bufA @ aw2 + ab2 (registers)
    {
        const float b2 = ab2[c];
#pragma unroll
        for (int k = 0; k < KNN; ++k) acc[k] = b2;
        for (int j = 0; j < D; j += 4) {
            const float w0 = aw2[(j + 0) * D + c], w1 = aw2[(j + 1) * D + c];
            const float w2 = aw2[(j + 2) * D + c], w3 = aw2[(j + 3) * D + c];
#pragma unroll
            for (int k = 0; k < KNN; ++k) {
                const float4 h = *(const float4*)&bufA[k][j];
                acc[k] = fmaf(h.x, w0, acc[k]);
                acc[k] = fmaf(h.y, w1, acc[k]);
                acc[k] = fmaf(h.z, w2, acc[k]);
                acc[k] = fmaf(h.w, w3, acc[k]);
            }
        }
    }

    // Phase F: softmax over k (thread-local) + weighted sum of (v_g + delta)
    {
        float m = acc[0];
#pragma unroll
        for (int k = 1; k < KNN; ++k) m = fmaxf(m, acc[k]);
        float s = 0.f;
#pragma unroll
        for (int k = 0; k < KNN; ++k) { acc[k] = expf(acc[k] - m); s += acc[k]; }
        const float inv = 1.f / s;
        float o = 0.f;
#pragma unroll
        for (int k = 0; k < KNN; ++k) {
            const float vg = vbuf[(size_t)nbr[k] * D + c];
            o = fmaf(acc[k] * inv, vg + delta[k], o);
        }
        out[(size_t)n * D + c] = o;
    }
}

// ---------------------------------------------------------------------------
extern "C" void kernel_launch(void* const* d_in, const int* in_sizes, int n_in,
                              void* d_out, int out_size, void* d_ws, size_t ws_size,
                              hipStream_t stream) {
    const float* xyz = (const float*)d_in[0];
    const float* feat = (const float*)d_in[1];
    const float* wq = (const float*)d_in[2];
    const float* bq = (const float*)d_in[3];
    const float* wk = (const float*)d_in[4];
    const float* bk = (const float*)d_in[5];
    const float* wv = (const float*)d_in[6];
    const float* bv = (const float*)d_in[7];
    const float* pw1 = (const float*)d_in[8];
    const float* pb1 = (const float*)d_in[9];
    const float* pw2 = (const float*)d_in[10];
    const float* pb2 = (const float*)d_in[11];
    const float* aw1 = (const float*)d_in[12];
    const float* ab1 = (const float*)d_in[13];
    const float* aw2 = (const float*)d_in[14];
    const float* ab2 = (const float*)d_in[15];

    float* ws = (float*)d_ws;
    float* qbuf = ws;                       // 16384*128
    float* kbuf = ws + 2097152;             // 16384*128
    float* vbuf = ws + 4194304;             // 16384*128
    float* pdist = ws + 6291456;            // 16384*64
    int* pidx = (int*)(ws + 7340032);       // 16384*64
    int* knn = (int*)(ws + 8388608);        // 16384*16
    float* out = (float*)d_out;

    hipLaunchKernelGGL(knn_partial, dim3(256, NCHUNK), dim3(QPB), 0, stream, xyz, pdist, pidx);
    hipLaunchKernelGGL(knn_merge, dim3(64), dim3(256), 0, stream, pdist, pidx, knn);
    hipLaunchKernelGGL(qkv_kernel, dim3(256), dim3(256), 0, stream,
                       feat, wq, bq, wk, bk, wv, bv, qbuf, kbuf, vbuf);
    hipLaunchKernelGGL(fused_kernel, dim3(16384), dim3(128), 0, stream,
                       xyz, qbuf, kbuf, vbuf, knn,
                       pw1, pb1, pw2, pb2, aw1, ab1, aw2, ab2, out);
}

// Round 2
// 738.853 us; speedup vs baseline: 1.4560x; 1.4560x over previous
//
#include <hip/hip_runtime.h>
#include <math.h>

typedef unsigned short u16;
typedef unsigned int u32;
typedef __attribute__((ext_vector_type(8))) short short8b;  // 8 x bf16
typedef __attribute__((ext_vector_type(4))) float f32x4;

#define N_PTS 8192
#define NTOT 16384
#define D 128
#define KNN 16
#define NCHUNK 16
#define CHUNK (N_PTS / NCHUNK)   // 512
#define QPB 64

__device__ __forceinline__ u16 f2bf(float x) {
    u32 u = __float_as_uint(x);
    u = (u + 0x7FFFu + ((u >> 16) & 1u)) >> 16;
    return (u16)u;
}

// ---------------------------------------------------------------------------
// Kernel 1: partial KNN. grid (256, 16), block 64. Transposed output layout:
// pdist[(chunk*16+s)*16384 + g] for coalesced merge reads.
// ---------------------------------------------------------------------------
__global__ __launch_bounds__(QPB) void knn_partial(const float* __restrict__ xyz,
                                                   float* __restrict__ pdist,
                                                   int* __restrict__ pidx) {
    __shared__ float4 tile[CHUNK];   // 8 KB
    const int qg = blockIdx.x;
    const int chunk = blockIdx.y;
    const int g = qg * QPB + threadIdx.x;
    const int b = g >> 13;
    const int n = g & (N_PTS - 1);
    const float* X = xyz + (size_t)b * N_PTS * 3;

    const float qx = X[n * 3 + 0];
    const float qy = X[n * 3 + 1];
    const float qz = X[n * 3 + 2];
    const float qn = qx * qx + qy * qy + qz * qz;

    const int cbase = chunk * CHUNK;
    for (int i = threadIdx.x; i < CHUNK; i += QPB) {
        const float x = X[(cbase + i) * 3 + 0];
        const float y = X[(cbase + i) * 3 + 1];
        const float z = X[(cbase + i) * 3 + 2];
        tile[i] = make_float4(x, y, z, x * x + y * y + z * z);
    }
    __syncthreads();

    float dist[KNN];
    int idx[KNN];
#pragma unroll
    for (int s = 0; s < KNN; ++s) { dist[s] = 1e30f; idx[s] = 0; }

#pragma unroll 4
    for (int j = 0; j < CHUNK; ++j) {
        const float4 c = tile[j];
        const float dot = qx * c.x + qy * c.y + qz * c.z;
        const float d = fmaf(-2.f, dot, qn + c.w);
        if (d < dist[KNN - 1]) {
            dist[KNN - 1] = d;
            idx[KNN - 1] = cbase + j;
#pragma unroll
            for (int s = KNN - 1; s > 0; --s) {
                if (dist[s] < dist[s - 1]) {
                    const float td = dist[s]; dist[s] = dist[s - 1]; dist[s - 1] = td;
                    const int ti = idx[s]; idx[s] = idx[s - 1]; idx[s - 1] = ti;
                }
            }
        }
    }

#pragma unroll
    for (int s = 0; s < KNN; ++s) {
        pdist[(size_t)(chunk * KNN + s) * NTOT + g] = dist[s];
        pidx[(size_t)(chunk * KNN + s) * NTOT + g] = idx[s] + b * N_PTS;
    }
}

// ---------------------------------------------------------------------------
// Kernel 2: merge 16 sorted partial lists. grid 64, block 256. Coalesced.
// ---------------------------------------------------------------------------
__global__ __launch_bounds__(256) void knn_merge(const float* __restrict__ pdist,
                                                 const int* __restrict__ pidx,
                                                 int* __restrict__ knn_out) {
    const int g = blockIdx.x * 256 + threadIdx.x;
    float dist[KNN];
    int idx[KNN];
#pragma unroll
    for (int s = 0; s < KNN; ++s) { dist[s] = 1e30f; idx[s] = 0; }

    for (int t = 0; t < NCHUNK * KNN; ++t) {
        const float d = pdist[(size_t)t * NTOT + g];
        const int id = pidx[(size_t)t * NTOT + g];
        if (d < dist[KNN - 1]) {
            dist[KNN - 1] = d;
            idx[KNN - 1] = id;
#pragma unroll
            for (int s = KNN - 1; s > 0; --s) {
                if (dist[s] < dist[s - 1]) {
                    const float td = dist[s]; dist[s] = dist[s - 1]; dist[s - 1] = td;
                    const int ti = idx[s]; idx[s] = idx[s - 1]; idx[s - 1] = ti;
                }
            }
        }
    }
#pragma unroll
    for (int s = 0; s < KNN; ++s) knn_out[g * KNN + s] = idx[s];
}

// ---------------------------------------------------------------------------
// Kernel 3: q/k/v projections (fp32 VALU, unchanged structure).
// ---------------------------------------------------------------------------
__global__ __launch_bounds__(256) void qkv_kernel(const float* __restrict__ feat,
                                                  const float* __restrict__ wq, const float* __restrict__ bq,
                                                  const float* __restrict__ wk, const float* __restrict__ bk,
                                                  const float* __restrict__ wv, const float* __restrict__ bv,
                                                  float* __restrict__ qbuf, float* __restrict__ kbuf,
                                                  float* __restrict__ vbuf) {
    __shared__ float ftile[64][D];
    const int r0 = blockIdx.x * 64;

    const float* src = feat + (size_t)r0 * D;
    for (int i = threadIdx.x; i < 64 * D / 4; i += 256) {
        ((float4*)&ftile[0][0])[i] = ((const float4*)src)[i];
    }
    __syncthreads();

    const int col = threadIdx.x & (D - 1);
    const int rbase = (threadIdx.x >> 7) * 32;

    float accq[32], acck[32], accv[32];
    const float bqv = bq[col], bkv = bk[col], bvv = bv[col];
#pragma unroll
    for (int r = 0; r < 32; ++r) { accq[r] = bqv; acck[r] = bkv; accv[r] = bvv; }

    for (int i = 0; i < D; i += 4) {
        const float wq0 = wq[(i + 0) * D + col], wq1 = wq[(i + 1) * D + col];
        const float wq2 = wq[(i + 2) * D + col], wq3 = wq[(i + 3) * D + col];
        const float wk0 = wk[(i + 0) * D + col], wk1 = wk[(i + 1) * D + col];
        const float wk2 = wk[(i + 2) * D + col], wk3 = wk[(i + 3) * D + col];
        const float wv0 = wv[(i + 0) * D + col], wv1 = wv[(i + 1) * D + col];
        const float wv2 = wv[(i + 2) * D + col], wv3 = wv[(i + 3) * D + col];
#pragma unroll
        for (int r = 0; r < 32; ++r) {
            const float4 f = *(const float4*)&ftile[rbase + r][i];
            accq[r] = fmaf(f.x, wq0, accq[r]); accq[r] = fmaf(f.y, wq1, accq[r]);
            accq[r] = fmaf(f.z, wq2, accq[r]); accq[r] = fmaf(f.w, wq3, accq[r]);
            acck[r] = fmaf(f.x, wk0, acck[r]); acck[r] = fmaf(f.y, wk1, acck[r]);
            acck[r] = fmaf(f.z, wk2, acck[r]); acck[r] = fmaf(f.w, wk3, acck[r]);
            accv[r] = fmaf(f.x, wv0, accv[r]); accv[r] = fmaf(f.y, wv1, accv[r]);
            accv[r] = fmaf(f.z, wv2, accv[r]); accv[r] = fmaf(f.w, wv3, accv[r]);
        }
    }
#pragma unroll
    for (int r = 0; r < 32; ++r) {
        const size_t o = (size_t)(r0 + rbase + r) * D + col;
        qbuf[o] = accq[r]; kbuf[o] = acck[r]; vbuf[o] = accv[r];
    }
}

// ---------------------------------------------------------------------------
// Kernel 4: pack weights into bf16 B-fragment order.
// Layout (u16 units): [0,4096)        pw1 padded to K=32: (t*64+l)*8+j
//                     [4096 + m*16384) pw2/aw1/aw2: ((q*8+t)*64+l)*8+j
// B-frag element: lane l, slot j -> B[k = q*32 + 8*(l>>4) + j][col = t*16 + (l&15)]
// ---------------------------------------------------------------------------
__global__ __launch_bounds__(256) void pack_w(const float* __restrict__ pw1,
                                              const float* __restrict__ pw2,
                                              const float* __restrict__ aw1,
                                              const float* __restrict__ aw2,
                                              u16* __restrict__ wp) {
    const int i = blockIdx.x * 256 + threadIdx.x;
    if (i >= 53248) return;
    float v;
    if (i < 4096) {
        const int j = i & 7, l = (i >> 3) & 63, t = (i >> 9) & 7;
        const int k = 8 * (l >> 4) + j;
        const int col = t * 16 + (l & 15);
        v = (k < 3) ? pw1[k * D + col] : 0.f;
    } else {
        const int i2 = i - 4096;
        const int m = i2 >> 14;
        const int r = i2 & 16383;
        const int j = r & 7, l = (r >> 3) & 63, t = (r >> 9) & 7, q = r >> 12;
        const float* w = (m == 0) ? pw2 : (m == 1) ? aw1 : aw2;
        v = w[(q * 32 + 8 * (l >> 4) + j) * D + t * 16 + (l & 15)];
    }
    wp[i] = f2bf(v);
}

// ---------------------------------------------------------------------------
// Kernel 5: fused point transformer with MFMA.
// Block = 512 threads (8 waves); wave = 1 point per iteration, 8 iterations.
// LDS: packed weights 104 KB + per-wave 4 KB swizzled bf16 A-buffer.
// ---------------------------------------------------------------------------
__device__ __forceinline__ void store_tile(char* ab, int grp, int c16,
                                           const f32x4* acc, bool dorelu) {
#pragma unroll
    for (int t = 0; t < 8; ++t) {
#pragma unroll
        for (int r = 0; r < 4; ++r) {
            const int row = grp * 4 + r;
            const int col = t * 16 + c16;
            float v = acc[t][r];
            if (dorelu) v = fmaxf(v, 0.f);
            const int byte = (row * 256 + col * 2) ^ ((row & 7) << 4);
            *(u16*)(ab + byte) = f2bf(v);
        }
    }
}

__device__ __forceinline__ void matmul128(const char* ab, const u16* wbase,
                                          int lane, int grp, int c16,
                                          const float* bias_row, f32x4* acc) {
#pragma unroll
    for (int t = 0; t < 8; ++t) {
        const float b = bias_row[t * 16 + c16];
        acc[t] = (f32x4){b, b, b, b};
    }
    short8b a[4];
#pragma unroll
    for (int q = 0; q < 4; ++q) {
        const int byte = (c16 * 256 + (q * 32 + grp * 8) * 2) ^ ((c16 & 7) << 4);
        a[q] = *(const short8b*)(ab + byte);
    }
#pragma unroll
    for (int q = 0; q < 4; ++q) {
#pragma unroll
        for (int t = 0; t < 8; ++t) {
            const short8b bb = *(const short8b*)((const char*)wbase + ((size_t)((q * 8 + t) * 64 + lane)) * 16);
            acc[t] = __builtin_amdgcn_mfma_f32_16x16x32_bf16(a[q], bb, acc[t], 0, 0, 0);
        }
    }
}

__global__ __launch_bounds__(512, 2) void fused_mfma(const float* __restrict__ xyz,
                                                     const float* __restrict__ qbuf,
                                                     const float* __restrict__ kbuf,
                                                     const float* __restrict__ vbuf,
                                                     const int* __restrict__ knn_in,
                                                     const u16* __restrict__ wpack,
                                                     const float* __restrict__ pb1,
                                                     const float* __restrict__ pb2,
                                                     const float* __restrict__ ab1,
                                                     const float* __restrict__ ab2,
                                                     float* __restrict__ out) {
    __shared__ __align__(16) u16 wlds[53248];       // 104 KB packed weights
    __shared__ float blds[4][D];                    // biases
    __shared__ __align__(16) char abuf_all[8][4096]; // per-wave A-buffer (bf16, swizzled)
    __shared__ int nbr_lds[8][16];

    const int tid = threadIdx.x;
    {
        const uint4* s = (const uint4*)wpack;
        uint4* d = (uint4*)wlds;
        for (int i = tid; i < 6656; i += 512) d[i] = s[i];
        const int b = tid >> 7, e = tid & 127;
        const float* bp = (b == 0) ? pb1 : (b == 1) ? pb2 : (b == 2) ? ab1 : ab2;
        blds[b][e] = bp[e];
    }
    __syncthreads();

    const int wid = tid >> 6, lane = tid & 63;
    const int c16 = lane & 15, grp = lane >> 4;
    char* ab = abuf_all[wid];
    int* nbr = nbr_lds[wid];

    for (int it = 0; it < 8; ++it) {
        const int n = (blockIdx.x * 8 + wid) * 8 + it;

        // --- neighbor setup (lanes 0..15) ---
        float dx = 0.f, dy = 0.f, dz = 0.f;
        if (lane < 16) {
            const int nid = knn_in[n * KNN + lane];
            nbr[lane] = nid;
            dx = xyz[n * 3 + 0] - xyz[nid * 3 + 0];
            dy = xyz[n * 3 + 1] - xyz[nid * 3 + 1];
            dz = xyz[n * 3 + 2] - xyz[nid * 3 + 2];
        }

        f32x4 acc[8];
        // --- h1 = relu(pos_diff @ pw1 + pb1), K=32 padded, 8 MFMA ---
        {
            short8b afrag;
#pragma unroll
            for (int j = 0; j < 8; ++j) afrag[j] = 0;
            if (lane < 16) {
                afrag[0] = (short)f2bf(dx);
                afrag[1] = (short)f2bf(dy);
                afrag[2] = (short)f2bf(dz);
            }
#pragma unroll
            for (int t = 0; t < 8; ++t) {
                const float b = blds[0][t * 16 + c16];
                acc[t] = (f32x4){b, b, b, b};
            }
#pragma unroll
            for (int t = 0; t < 8; ++t) {
                const short8b bb = *(const short8b*)((const char*)wlds + (size_t)(t * 64 + lane) * 16);
                acc[t] = __builtin_amdgcn_mfma_f32_16x16x32_bf16(afrag, bb, acc[t], 0, 0, 0);
            }
            store_tile(ab, grp, c16, acc, true);
        }

        // --- delta = h1 @ pw2 + pb2 (kept in regs, D-layout) ---
        f32x4 del[8];
        matmul128(ab, wlds + 4096, lane, grp, c16, blds[1], del);

        // --- attn_in = q - k_g + delta -> A-buffer (bf16) ---
        int rown[4];
#pragma unroll
        for (int r = 0; r < 4; ++r) rown[r] = nbr[grp * 4 + r];
#pragma unroll
        for (int t = 0; t < 8; ++t) {
            const float qv = qbuf[(size_t)n * D + t * 16 + c16];
#pragma unroll
            for (int r = 0; r < 4; ++r) {
                const float kg = kbuf[(size_t)rown[r] * D + t * 16 + c16];
                const float v = qv - kg + del[t][r];
                const int row = grp * 4 + r;
                const int col = t * 16 + c16;
                const int byte = (row * 256 + col * 2) ^ ((row & 7) << 4);
                *(u16*)(ab + byte) = f2bf(v);
            }
        }

        // --- h2 = relu(attn_in @ aw1 + ab1) -> A-buffer ---
        matmul128(ab, wlds + 20480, lane, grp, c16, blds[2], acc);
        store_tile(ab, grp, c16, acc, true);

        // --- logits = h2 @ aw2 + ab2 ---
        matmul128(ab, wlds + 36864, lane, grp, c16, blds[3], acc);

        // --- softmax over 16 neighbors (per channel) + weighted sum ---
        float ov[8];
#pragma unroll
        for (int t = 0; t < 8; ++t) {
            float m = fmaxf(fmaxf(acc[t][0], acc[t][1]), fmaxf(acc[t][2], acc[t][3]));
            m = fmaxf(m, __shfl_xor(m, 16));
            m = fmaxf(m, __shfl_xor(m, 32));
            float e[4];
            float s = 0.f;
#pragma unroll
            for (int r = 0; r < 4; ++r) { e[r] = __expf(acc[t][r] - m); s += e[r]; }
            s += __shfl_xor(s, 16);
            s += __shfl_xor(s, 32);
            const float inv = 1.f / s;
            float o = 0.f;
#pragma unroll
            for (int r = 0; r < 4; ++r) {
                const float vg = vbuf[(size_t)rown[r] * D + t * 16 + c16];
                o = fmaf(e[r] * inv, vg + del[t][r], o);
            }
            o += __shfl_xor(o, 16);
            o += __shfl_xor(o, 32);
            ov[t] = o;
        }
        float v1 = ov[0], v2 = ov[4];
        if (grp == 1) { v1 = ov[1]; v2 = ov[5]; }
        if (grp == 2) { v1 = ov[2]; v2 = ov[6]; }
        if (grp == 3) { v1 = ov[3]; v2 = ov[7]; }
        out[(size_t)n * D + grp * 16 + c16] = v1;
        out[(size_t)n * D + 64 + grp * 16 + c16] = v2;
    }
}

// ---------------------------------------------------------------------------
extern "C" void kernel_launch(void* const* d_in, const int* in_sizes, int n_in,
                              void* d_out, int out_size, void* d_ws, size_t ws_size,
                              hipStream_t stream) {
    const float* xyz = (const float*)d_in[0];
    const float* feat = (const float*)d_in[1];
    const float* wq = (const float*)d_in[2];
    const float* bq = (const float*)d_in[3];
    const float* wk = (const float*)d_in[4];
    const float* bk = (const float*)d_in[5];
    const float* wv = (const float*)d_in[6];
    const float* bv = (const float*)d_in[7];
    const float* pw1 = (const float*)d_in[8];
    const float* pb1 = (const float*)d_in[9];
    const float* pw2 = (const float*)d_in[10];
    const float* pb2 = (const float*)d_in[11];
    const float* aw1 = (const float*)d_in[12];
    const float* ab1 = (const float*)d_in[13];
    const float* aw2 = (const float*)d_in[14];
    const float* ab2 = (const float*)d_in[15];

    float* ws = (float*)d_ws;
    // Overlay region: pdist/pidx (knn phase) then qbuf/kbuf/vbuf/wpack (mlp phase)
    float* pdist = ws;                        // 4,194,304 f32
    int* pidx = (int*)(ws + 4194304);         // 4,194,304 i32
    float* qbuf = ws;                         // 2,097,152 f32
    float* kbuf = ws + 2097152;               // 2,097,152 f32
    float* vbuf = ws + 4194304;               // 2,097,152 f32
    u16* wpack = (u16*)(ws + 6291456);        // 53,248 u16
    int* knn = (int*)(ws + 8388608);          // 262,144 i32
    float* out = (float*)d_out;

    hipLaunchKernelGGL(knn_partial, dim3(256, NCHUNK), dim3(QPB), 0, stream, xyz, pdist, pidx);
    hipLaunchKernelGGL(knn_merge, dim3(64), dim3(256), 0, stream, pdist, pidx, knn);
    hipLaunchKernelGGL(qkv_kernel, dim3(256), dim3(256), 0, stream,
                       feat, wq, bq, wk, bk, wv, bv, qbuf, kbuf, vbuf);
    hipLaunchKernelGGL(pack_w, dim3(208), dim3(256), 0, stream, pw1, pw2, aw1, aw2, wpack);
    hipLaunchKernelGGL(fused_mfma, dim3(256), dim3(512), 0, stream,
                       xyz, qbuf, kbuf, vbuf, knn, wpack,
                       pb1, pb2, ab1, ab2, out);
}

// Round 3
// 438.105 us; speedup vs baseline: 2.4555x; 1.6865x over previous
//
#include <hip/hip_runtime.h>
#include <math.h>

typedef unsigned short u16;
typedef unsigned int u32;
typedef __attribute__((ext_vector_type(8))) short short8b;  // 8 x bf16
typedef __attribute__((ext_vector_type(4))) float f32x4;

#define N_PTS 8192
#define NTOT 16384
#define D 128
#define KNN 16
#define NCHUNK 8
#define CHUNK (N_PTS / NCHUNK)   // 1024

__device__ __forceinline__ u16 f2bf(float x) {
    u32 u = __float_as_uint(x);
    u = (u + 0x7FFFu + ((u >> 16) & 1u)) >> 16;
    return (u16)u;
}
__device__ __forceinline__ float bf2f(u16 v) {
    return __uint_as_float(((u32)v) << 16);
}

// ---------------------------------------------------------------------------
// Kernel 1a: residue-min slots. grid (256, 8), block 64.
// slots[s] = min over candidates with local j%16==s. One v_min per candidate,
// branch-free. max_s over all chunks' slots >= exact 16th distance (16
// distinct candidates' max >= T16).
// ---------------------------------------------------------------------------
__global__ __launch_bounds__(64) void knn_minslots(const float* __restrict__ xyz,
                                                   float* __restrict__ pmins) {
    __shared__ float4 tile[CHUNK];   // 16 KB
    const int g = blockIdx.x * 64 + threadIdx.x;
    const int b = g >> 13;
    const int n = g & (N_PTS - 1);
    const float* X = xyz + (size_t)b * N_PTS * 3;

    const float qx = X[n * 3 + 0];
    const float qy = X[n * 3 + 1];
    const float qz = X[n * 3 + 2];
    const float qn = qx * qx + qy * qy + qz * qz;

    const int cbase = blockIdx.y * CHUNK;
    for (int i = threadIdx.x; i < CHUNK; i += 64) {
        const float x = X[(cbase + i) * 3 + 0];
        const float y = X[(cbase + i) * 3 + 1];
        const float z = X[(cbase + i) * 3 + 2];
        tile[i] = make_float4(x, y, z, x * x + y * y + z * z);
    }
    __syncthreads();

    float slots[16];
#pragma unroll
    for (int s = 0; s < 16; ++s) slots[s] = 1e30f;

    for (int j0 = 0; j0 < CHUNK; j0 += 16) {
#pragma unroll
        for (int s = 0; s < 16; ++s) {
            const float4 c = tile[j0 + s];
            const float dot = qx * c.x + qy * c.y + qz * c.z;
            const float d = fmaf(-2.f, dot, qn + c.w);
            slots[s] = fminf(slots[s], d);
        }
    }
#pragma unroll
    for (int s = 0; s < 16; ++s)
        pmins[(size_t)(blockIdx.y * 16 + s) * NTOT + g] = slots[s];
}

// ---------------------------------------------------------------------------
// Kernel 1b: T'[g] = nextup(max_s min_chunks slots) — safe seed threshold.
// ---------------------------------------------------------------------------
__global__ __launch_bounds__(256) void knn_thresh(const float* __restrict__ pmins,
                                                  float* __restrict__ thr) {
    const int g = blockIdx.x * 256 + threadIdx.x;
    float m[16];
#pragma unroll
    for (int s = 0; s < 16; ++s) m[s] = 1e30f;
    for (int ch = 0; ch < NCHUNK; ++ch) {
#pragma unroll
        for (int s = 0; s < 16; ++s)
            m[s] = fminf(m[s], pmins[(size_t)(ch * 16 + s) * NTOT + g]);
    }
    float T = m[0];
#pragma unroll
    for (int s = 1; s < 16; ++s) T = fmaxf(T, m[s]);
    u32 u = __float_as_uint(T);
    u = (T >= 0.f) ? (u + 1u) : (u - 1u);   // nextafter toward +inf
    thr[g] = __uint_as_float(u);
}

// ---------------------------------------------------------------------------
// Kernel 2: seeded exact selection. grid (256, 8), block 64.
// List pre-seeded with T' > T16: only true-survivor candidates (~50/query over
// all chunks) enter the insert body. Same insertion/tie semantics as validated
// round-1 kernel; fully deterministic.
// ---------------------------------------------------------------------------
__global__ __launch_bounds__(64) void knn_select(const float* __restrict__ xyz,
                                                 const float* __restrict__ thr,
                                                 float* __restrict__ pdist,
                                                 int* __restrict__ pidx) {
    __shared__ float4 tile[CHUNK];   // 16 KB
    const int g = blockIdx.x * 64 + threadIdx.x;
    const int b = g >> 13;
    const int n = g & (N_PTS - 1);
    const float* X = xyz + (size_t)b * N_PTS * 3;

    const float qx = X[n * 3 + 0];
    const float qy = X[n * 3 + 1];
    const float qz = X[n * 3 + 2];
    const float qn = qx * qx + qy * qy + qz * qz;

    const int cbase = blockIdx.y * CHUNK;
    for (int i = threadIdx.x; i < CHUNK; i += 64) {
        const float x = X[(cbase + i) * 3 + 0];
        const float y = X[(cbase + i) * 3 + 1];
        const float z = X[(cbase + i) * 3 + 2];
        tile[i] = make_float4(x, y, z, x * x + y * y + z * z);
    }
    __syncthreads();

    const float seed = thr[g];
    float dist[KNN];
    int idx[KNN];
#pragma unroll
    for (int s = 0; s < KNN; ++s) { dist[s] = seed; idx[s] = 0; }

#pragma unroll 4
    for (int j = 0; j < CHUNK; ++j) {
        const float4 c = tile[j];
        const float dot = qx * c.x + qy * c.y + qz * c.z;
        const float d = fmaf(-2.f, dot, qn + c.w);
        if (d < dist[KNN - 1]) {
            dist[KNN - 1] = d;
            idx[KNN - 1] = cbase + j;
#pragma unroll
            for (int s = KNN - 1; s > 0; --s) {
                if (dist[s] < dist[s - 1]) {
                    const float td = dist[s]; dist[s] = dist[s - 1]; dist[s - 1] = td;
                    const int ti = idx[s]; idx[s] = idx[s - 1]; idx[s - 1] = ti;
                }
            }
        }
    }

#pragma unroll
    for (int s = 0; s < KNN; ++s) {
        pdist[(size_t)(blockIdx.y * KNN + s) * NTOT + g] = dist[s];
        pidx[(size_t)(blockIdx.y * KNN + s) * NTOT + g] = idx[s] + b * N_PTS;
    }
}

// ---------------------------------------------------------------------------
// Kernel 3: merge 8 sorted partial lists (seeds always lose). Coalesced.
// ---------------------------------------------------------------------------
__global__ __launch_bounds__(256) void knn_merge(const float* __restrict__ pdist,
                                                 const int* __restrict__ pidx,
                                                 int* __restrict__ knn_out) {
    const int g = blockIdx.x * 256 + threadIdx.x;
    float dist[KNN];
    int idx[KNN];
#pragma unroll
    for (int s = 0; s < KNN; ++s) { dist[s] = 1e30f; idx[s] = 0; }

    for (int t = 0; t < NCHUNK * KNN; ++t) {
        const float d = pdist[(size_t)t * NTOT + g];
        const int id = pidx[(size_t)t * NTOT + g];
        if (d < dist[KNN - 1]) {
            dist[KNN - 1] = d;
            idx[KNN - 1] = id;
#pragma unroll
            for (int s = KNN - 1; s > 0; --s) {
                if (dist[s] < dist[s - 1]) {
                    const float td = dist[s]; dist[s] = dist[s - 1]; dist[s - 1] = td;
                    const int ti = idx[s]; idx[s] = idx[s - 1]; idx[s - 1] = ti;
                }
            }
        }
    }
#pragma unroll
    for (int s = 0; s < KNN; ++s) knn_out[g * KNN + s] = idx[s];
}

// ---------------------------------------------------------------------------
// Kernel 4: q/k/v projections. q fp32; k,v bf16 (halves gather traffic).
// ---------------------------------------------------------------------------
__global__ __launch_bounds__(256) void qkv_kernel(const float* __restrict__ feat,
                                                  const float* __restrict__ wq, const float* __restrict__ bq,
                                                  const float* __restrict__ wk, const float* __restrict__ bk,
                                                  const float* __restrict__ wv, const float* __restrict__ bv,
                                                  float* __restrict__ qbuf, u16* __restrict__ kb,
                                                  u16* __restrict__ vb) {
    __shared__ float ftile[64][D];
    const int r0 = blockIdx.x * 64;

    const float* src = feat + (size_t)r0 * D;
    for (int i = threadIdx.x; i < 64 * D / 4; i += 256) {
        ((float4*)&ftile[0][0])[i] = ((const float4*)src)[i];
    }
    __syncthreads();

    const int col = threadIdx.x & (D - 1);
    const int rbase = (threadIdx.x >> 7) * 32;

    float accq[32], acck[32], accv[32];
    const float bqv = bq[col], bkv = bk[col], bvv = bv[col];
#pragma unroll
    for (int r = 0; r < 32; ++r) { accq[r] = bqv; acck[r] = bkv; accv[r] = bvv; }

    for (int i = 0; i < D; i += 4) {
        const float wq0 = wq[(i + 0) * D + col], wq1 = wq[(i + 1) * D + col];
        const float wq2 = wq[(i + 2) * D + col], wq3 = wq[(i + 3) * D + col];
        const float wk0 = wk[(i + 0) * D + col], wk1 = wk[(i + 1) * D + col];
        const float wk2 = wk[(i + 2) * D + col], wk3 = wk[(i + 3) * D + col];
        const float wv0 = wv[(i + 0) * D + col], wv1 = wv[(i + 1) * D + col];
        const float wv2 = wv[(i + 2) * D + col], wv3 = wv[(i + 3) * D + col];
#pragma unroll
        for (int r = 0; r < 32; ++r) {
            const float4 f = *(const float4*)&ftile[rbase + r][i];
            accq[r] = fmaf(f.x, wq0, accq[r]); accq[r] = fmaf(f.y, wq1, accq[r]);
            accq[r] = fmaf(f.z, wq2, accq[r]); accq[r] = fmaf(f.w, wq3, accq[r]);
            acck[r] = fmaf(f.x, wk0, acck[r]); acck[r] = fmaf(f.y, wk1, acck[r]);
            acck[r] = fmaf(f.z, wk2, acck[r]); acck[r] = fmaf(f.w, wk3, acck[r]);
            accv[r] = fmaf(f.x, wv0, accv[r]); accv[r] = fmaf(f.y, wv1, accv[r]);
            accv[r] = fmaf(f.z, wv2, accv[r]); accv[r] = fmaf(f.w, wv3, accv[r]);
        }
    }
#pragma unroll
    for (int r = 0; r < 32; ++r) {
        const size_t o = (size_t)(r0 + rbase + r) * D + col;
        qbuf[o] = accq[r]; kb[o] = f2bf(acck[r]); vb[o] = f2bf(accv[r]);
    }
}

// ---------------------------------------------------------------------------
// Kernel 5: pack pw2/aw1/aw2 into bf16 B-fragment order (validated mapping).
// u16 offset m*16384; frag f=(q*8+t): element B[k=q*32+8*(l>>4)+j][t*16+(l&15)]
// ---------------------------------------------------------------------------
__global__ __launch_bounds__(256) void pack_w(const float* __restrict__ pw2,
                                              const float* __restrict__ aw1,
                                              const float* __restrict__ aw2,
                                              u16* __restrict__ wp) {
    const int i = blockIdx.x * 256 + threadIdx.x;
    const int m = i >> 14;
    const int r = i & 16383;
    const int j = r & 7, l = (r >> 3) & 63, t = (r >> 9) & 7, q = r >> 12;
    const float* w = (m == 0) ? pw2 : (m == 1) ? aw1 : aw2;
    wp[i] = f2bf(w[(q * 32 + 8 * (l >> 4) + j) * D + t * 16 + (l & 15)]);
}

// ---------------------------------------------------------------------------
// Kernel 6: fused point transformer, GEMM-batched.
// 256 blocks x 1024 threads (16 waves = 4/SIMD). Per group: 8 points = 128
// rows; A-tile [128][128] bf16 XOR-swizzled; weights resident in LDS.
// Wave (a=wid>>2, c2=wid&3) owns rows 32a..+32 (2 points) x cols 32c2..+32.
// ---------------------------------------------------------------------------
__device__ __forceinline__ void gemm_tile(const char* atile, const u16* wl, int mat,
                                          const float* brow, int a, int c2, int lane,
                                          f32x4 acc[2][2]) {
    const int c16 = lane & 15, grp = lane >> 4;
#pragma unroll
    for (int mt = 0; mt < 2; ++mt)
#pragma unroll
        for (int ct = 0; ct < 2; ++ct) {
            const float b = brow[c2 * 32 + ct * 16 + c16];
            acc[mt][ct] = (f32x4){b, b, b, b};
        }
#pragma unroll
    for (int q = 0; q < 4; ++q) {
        short8b af[2], bf[2];
#pragma unroll
        for (int mt = 0; mt < 2; ++mt) {
            const int row = (2 * a + mt) * 16 + c16;
            const int byte = (row * 256 + (q * 32 + grp * 8) * 2) ^ ((row & 7) << 4);
            af[mt] = *(const short8b*)(atile + byte);
        }
#pragma unroll
        for (int ct = 0; ct < 2; ++ct) {
            const int tg = c2 * 2 + ct;
            bf[ct] = *(const short8b*)((const char*)wl + (size_t)mat * 32768 +
                                       (size_t)((q * 8 + tg) * 64 + lane) * 16);
        }
#pragma unroll
        for (int mt = 0; mt < 2; ++mt)
#pragma unroll
            for (int ct = 0; ct < 2; ++ct)
                acc[mt][ct] = __builtin_amdgcn_mfma_f32_16x16x32_bf16(af[mt], bf[ct], acc[mt][ct], 0, 0, 0);
    }
}

__global__ __launch_bounds__(1024, 4) void fused_v3(const float* __restrict__ xyz,
                                                    const float* __restrict__ qbuf,
                                                    const u16* __restrict__ kb,
                                                    const u16* __restrict__ vb,
                                                    const int* __restrict__ knn_in,
                                                    const u16* __restrict__ wpack,
                                                    const float* __restrict__ pw1,
                                                    const float* __restrict__ pb1,
                                                    const float* __restrict__ pb2,
                                                    const float* __restrict__ ab1,
                                                    const float* __restrict__ ab2,
                                                    float* __restrict__ out) {
    __shared__ __align__(16) u16 wlds[49152];     // 96 KB: pw2, aw1, aw2
    __shared__ __align__(16) char atile[32768];   // [128][128] bf16 swizzled
    __shared__ float pw1s[3][D];
    __shared__ float pb1s[D];
    __shared__ float bias[3][D];                  // pb2, ab1, ab2
    __shared__ float diffs[128][4];
    __shared__ int nbrs[128];

    const int tid = threadIdx.x;
    {
        const uint4* s = (const uint4*)wpack;
        uint4* d = (uint4*)wlds;
        for (int i = tid; i < 6144; i += 1024) d[i] = s[i];
        if (tid < 384) pw1s[tid >> 7][tid & 127] = pw1[tid];
        if (tid < 128) pb1s[tid] = pb1[tid];
        else if (tid < 256) bias[0][tid & 127] = pb2[tid & 127];
        else if (tid < 512 && tid >= 384) bias[1][tid & 127] = ab1[tid & 127];
        else if (tid >= 512 && tid < 640) bias[2][tid & 127] = ab2[tid & 127];
    }

    const int wid = tid >> 6, lane = tid & 63;
    const int a = wid >> 2, c2 = wid & 3;
    const int c16 = lane & 15, grp = lane >> 4;

    for (int g = 0; g < 8; ++g) {
        const int p0 = blockIdx.x * 64 + g * 8;
        __syncthreads();   // protects atile/nbrs/diffs from previous group

        // P1: neighbor ids + pos diffs
        if (tid < 128) {
            const int pt = p0 + (tid >> 4);
            const int nb = knn_in[pt * KNN + (tid & 15)];
            nbrs[tid] = nb;
            diffs[tid][0] = xyz[pt * 3 + 0] - xyz[nb * 3 + 0];
            diffs[tid][1] = xyz[pt * 3 + 1] - xyz[nb * 3 + 1];
            diffs[tid][2] = xyz[pt * 3 + 2] - xyz[nb * 3 + 2];
        }
        __syncthreads();

        // P2: h1 = relu(pos_diff @ pw1 + pb1) -> atile (VALU, K=3)
        {
            const int row = tid >> 3;
            const int c0 = (tid & 7) * 16;
            const float d0 = diffs[row][0], d1 = diffs[row][1], d2 = diffs[row][2];
#pragma unroll
            for (int c = 0; c < 16; c += 2) {
                const int cc = c0 + c;
                float h0 = pb1s[cc];
                h0 = fmaf(d0, pw1s[0][cc], h0); h0 = fmaf(d1, pw1s[1][cc], h0); h0 = fmaf(d2, pw1s[2][cc], h0);
                float h1 = pb1s[cc + 1];
                h1 = fmaf(d0, pw1s[0][cc + 1], h1); h1 = fmaf(d1, pw1s[1][cc + 1], h1); h1 = fmaf(d2, pw1s[2][cc + 1], h1);
                const u32 packed = (u32)f2bf(fmaxf(h0, 0.f)) | ((u32)f2bf(fmaxf(h1, 0.f)) << 16);
                const int byte = (row * 256 + cc * 2) ^ ((row & 7) << 4);
                *(u32*)(atile + byte) = packed;
            }
        }
        __syncthreads();

        // P3: delta = h1 @ pw2 + pb2 (regs, C-layout)
        f32x4 del[2][2];
        gemm_tile(atile, wlds, 0, bias[0], a, c2, lane, del);
        __syncthreads();   // all A-reads done

        // P4: attn_in = q - k_g + delta -> atile
#pragma unroll
        for (int mt = 0; mt < 2; ++mt) {
            const int pt = p0 + 2 * a + mt;
#pragma unroll
            for (int ct = 0; ct < 2; ++ct) {
                const int col = c2 * 32 + ct * 16 + c16;
                const float qv = qbuf[(size_t)pt * D + col];
#pragma unroll
                for (int r = 0; r < 4; ++r) {
                    const int lrow = (2 * a + mt) * 16 + grp * 4 + r;
                    const int nb = nbrs[lrow];
                    const float kg = bf2f(kb[(size_t)nb * D + col]);
                    const float v = qv - kg + del[mt][ct][r];
                    const int byte = (lrow * 256 + col * 2) ^ ((lrow & 7) << 4);
                    *(u16*)(atile + byte) = f2bf(v);
                }
            }
        }
        __syncthreads();

        // P5: h2 = relu(attn_in @ aw1 + ab1)
        f32x4 acc[2][2];
        gemm_tile(atile, wlds, 1, bias[1], a, c2, lane, acc);
        __syncthreads();   // all A-reads done

        // P6: store relu(h2) -> atile
#pragma unroll
        for (int mt = 0; mt < 2; ++mt)
#pragma unroll
            for (int ct = 0; ct < 2; ++ct) {
                const int col = c2 * 32 + ct * 16 + c16;
#pragma unroll
                for (int r = 0; r < 4; ++r) {
                    const int lrow = (2 * a + mt) * 16 + grp * 4 + r;
                    const int byte = (lrow * 256 + col * 2) ^ ((lrow & 7) << 4);
                    *(u16*)(atile + byte) = f2bf(fmaxf(acc[mt][ct][r], 0.f));
                }
            }
        __syncthreads();

        // P7: logits = h2 @ aw2 + ab2
        gemm_tile(atile, wlds, 2, bias[2], a, c2, lane, acc);

        // P8: softmax over 16 neighbors (rows of M-tile) + weighted sum
        float om[2][2];
#pragma unroll
        for (int mt = 0; mt < 2; ++mt) {
#pragma unroll
            for (int ct = 0; ct < 2; ++ct) {
                const int col = c2 * 32 + ct * 16 + c16;
                // prefetch v_g
                float vg[4];
#pragma unroll
                for (int r = 0; r < 4; ++r) {
                    const int lrow = (2 * a + mt) * 16 + grp * 4 + r;
                    vg[r] = bf2f(vb[(size_t)nbrs[lrow] * D + col]);
                }
                float m = fmaxf(fmaxf(acc[mt][ct][0], acc[mt][ct][1]),
                                fmaxf(acc[mt][ct][2], acc[mt][ct][3]));
                m = fmaxf(m, __shfl_xor(m, 16));
                m = fmaxf(m, __shfl_xor(m, 32));
                float e[4], s = 0.f;
#pragma unroll
                for (int r = 0; r < 4; ++r) { e[r] = __expf(acc[mt][ct][r] - m); s += e[r]; }
                s += __shfl_xor(s, 16);
                s += __shfl_xor(s, 32);
                const float inv = 1.f / s;
                float o = 0.f;
#pragma unroll
                for (int r = 0; r < 4; ++r) o = fmaf(e[r] * inv, vg[r] + del[mt][ct][r], o);
                o += __shfl_xor(o, 16);
                o += __shfl_xor(o, 32);
                om[mt][ct] = o;
            }
        }
        float osel = om[0][0];
        if (grp == 1) osel = om[0][1];
        if (grp == 2) osel = om[1][0];
        if (grp == 3) osel = om[1][1];
        const int opt = p0 + 2 * a + (grp >> 1);
        out[(size_t)opt * D + c2 * 32 + (grp & 1) * 16 + c16] = osel;
    }
}

// ---------------------------------------------------------------------------
extern "C" void kernel_launch(void* const* d_in, const int* in_sizes, int n_in,
                              void* d_out, int out_size, void* d_ws, size_t ws_size,
                              hipStream_t stream) {
    const float* xyz = (const float*)d_in[0];
    const float* feat = (const float*)d_in[1];
    const float* wq = (const float*)d_in[2];
    const float* bq = (const float*)d_in[3];
    const float* wk = (const float*)d_in[4];
    const float* bk = (const float*)d_in[5];
    const float* wv = (const float*)d_in[6];
    const float* bv = (const float*)d_in[7];
    const float* pw1 = (const float*)d_in[8];
    const float* pb1 = (const float*)d_in[9];
    const float* pw2 = (const float*)d_in[10];
    const float* pb2 = (const float*)d_in[11];
    const float* aw1 = (const float*)d_in[12];
    const float* ab1 = (const float*)d_in[13];
    const float* aw2 = (const float*)d_in[14];
    const float* ab2 = (const float*)d_in[15];

    float* ws = (float*)d_ws;
    // knn phase (then overlaid by qkv/pack outputs):
    float* pmins = ws;                          // [8*16][16384] = 2,097,152 f32
    float* pdist = ws + 2097152;                // 2,097,152 f32
    int* pidx = (int*)(ws + 4194304);           // 2,097,152 i32
    // mlp phase overlays:
    float* qbuf = ws;                           // 2,097,152 f32
    u16* kb = (u16*)(ws + 2097152);             // 2,097,152 u16
    u16* vb = (u16*)(ws + 3145728);             // 2,097,152 u16
    u16* wpack = (u16*)(ws + 4194304);          // 49,152 u16
    // persistent:
    float* thr = ws + 6291456;                  // 16,384 f32
    int* knn = (int*)(ws + 6307840);            // 262,144 i32
    float* out = (float*)d_out;

    hipLaunchKernelGGL(knn_minslots, dim3(256, NCHUNK), dim3(64), 0, stream, xyz, pmins);
    hipLaunchKernelGGL(knn_thresh, dim3(64), dim3(256), 0, stream, pmins, thr);
    hipLaunchKernelGGL(knn_select, dim3(256, NCHUNK), dim3(64), 0, stream, xyz, thr, pdist, pidx);
    hipLaunchKernelGGL(knn_merge, dim3(64), dim3(256), 0, stream, pdist, pidx, knn);
    hipLaunchKernelGGL(qkv_kernel, dim3(256), dim3(256), 0, stream,
                       feat, wq, bq, wk, bk, wv, bv, qbuf, kb, vb);
    hipLaunchKernelGGL(pack_w, dim3(192), dim3(256), 0, stream, pw2, aw1, aw2, wpack);
    hipLaunchKernelGGL(fused_v3, dim3(256), dim3(1024), 0, stream,
                       xyz, qbuf, kb, vb, knn, wpack,
                       pw1, pb1, pb2, ab1, ab2, out);
}

// Round 4
// 408.394 us; speedup vs baseline: 2.6341x; 1.0728x over previous
//
#include <hip/hip_runtime.h>
#include <math.h>

typedef unsigned short u16;
typedef unsigned int u32;
typedef __attribute__((ext_vector_type(8))) short short8b;  // 8 x bf16
typedef __attribute__((ext_vector_type(4))) float f32x4;

#define N_PTS 8192
#define NTOT 16384
#define D 128
#define KNN 16
#define NCH_M 8            // minslots chunks (1024 cands)
#define NCH_S 16           // select chunks (512 cands)
#define CAP 20             // survivor cap per (query, select-chunk)

__device__ __forceinline__ u16 f2bf(float x) {
    u32 u = __float_as_uint(x);
    u = (u + 0x7FFFu + ((u >> 16) & 1u)) >> 16;
    return (u16)u;
}
__device__ __forceinline__ float bf2f(u16 v) {
    return __uint_as_float(((u32)v) << 16);
}

// ---------------------------------------------------------------------------
// Kernel 0: xyz4[i] = (x, y, z, 0.5*|p|^2)  — coalesced candidate table.
// ---------------------------------------------------------------------------
__global__ __launch_bounds__(256) void xyz4_prep(const float* __restrict__ xyz,
                                                 float4* __restrict__ xyz4) {
    const int i = blockIdx.x * 256 + threadIdx.x;
    const float x = xyz[i * 3 + 0], y = xyz[i * 3 + 1], z = xyz[i * 3 + 2];
    xyz4[i] = make_float4(x, y, z, 0.5f * (x * x + y * y + z * z));
}

// ---------------------------------------------------------------------------
// Kernel 1: residue-min slots in e-space. grid (64, 8), block 128, 2 q/thread.
// e = 0.5|c|^2 - q.c  (strictly monotone in squared distance per query).
// ---------------------------------------------------------------------------
__global__ __launch_bounds__(128) void knn_minslots(const float4* __restrict__ xyz4,
                                                    float* __restrict__ pmins) {
    __shared__ float4 tile[1024];   // 16 KB
    const int tid = threadIdx.x;
    const int qA = blockIdx.x * 256 + tid;
    const int qB = qA + 128;
    const int cbase = (qA >> 13) * N_PTS + blockIdx.y * 1024;

    const float4 a = xyz4[qA];
    const float4 b = xyz4[qB];

    for (int i = tid; i < 1024; i += 128) tile[i] = xyz4[cbase + i];
    __syncthreads();

    float sA[16], sB[16];
#pragma unroll
    for (int s = 0; s < 16; ++s) { sA[s] = 1e30f; sB[s] = 1e30f; }

    for (int j0 = 0; j0 < 1024; j0 += 16) {
#pragma unroll
        for (int s = 0; s < 16; ++s) {
            const float4 c = tile[j0 + s];
            const float eA = fmaf(-a.x, c.x, fmaf(-a.y, c.y, fmaf(-a.z, c.z, c.w)));
            const float eB = fmaf(-b.x, c.x, fmaf(-b.y, c.y, fmaf(-b.z, c.z, c.w)));
            sA[s] = fminf(sA[s], eA);
            sB[s] = fminf(sB[s], eB);
        }
    }
#pragma unroll
    for (int s = 0; s < 16; ++s) {
        pmins[(size_t)(blockIdx.y * 16 + s) * NTOT + qA] = sA[s];
        pmins[(size_t)(blockIdx.y * 16 + s) * NTOT + qB] = sB[s];
    }
}

// ---------------------------------------------------------------------------
// Kernel 2: T'[g] = nextup(max_s min_chunks slots) — safe threshold (> e16).
// ---------------------------------------------------------------------------
__global__ __launch_bounds__(256) void knn_thresh(const float* __restrict__ pmins,
                                                  float* __restrict__ thr) {
    const int g = blockIdx.x * 256 + threadIdx.x;
    float m[16];
#pragma unroll
    for (int s = 0; s < 16; ++s) m[s] = 1e30f;
    for (int ch = 0; ch < NCH_M; ++ch) {
#pragma unroll
        for (int s = 0; s < 16; ++s)
            m[s] = fminf(m[s], pmins[(size_t)(ch * 16 + s) * NTOT + g]);
    }
    float T = m[0];
#pragma unroll
    for (int s = 1; s < 16; ++s) T = fmaxf(T, m[s]);
    u32 u = __float_as_uint(T);
    u = (T >= 0.f) ? (u + 1u) : (u - 1u);   // nextafter toward +inf
    thr[g] = __uint_as_float(u);
}

// ---------------------------------------------------------------------------
// Kernel 3: filter-and-append selection. grid (32, 16), block 256, 2 q/thread.
// Appends (e, local j) of survivors (e < T') to per-(q,chunk) global lists.
// ---------------------------------------------------------------------------
__global__ __launch_bounds__(256) void knn_select(const float4* __restrict__ xyz4,
                                                  const float* __restrict__ thr,
                                                  float* __restrict__ dcomp,
                                                  u16* __restrict__ jcomp,
                                                  u32* __restrict__ counts) {
    __shared__ float4 tile[512];   // 8 KB
    const int tid = threadIdx.x;
    const int ch = blockIdx.y;
    const int qA = blockIdx.x * 512 + tid;
    const int qB = qA + 256;
    const int cbase = (qA >> 13) * N_PTS + ch * 512;

    const float4 a = xyz4[qA];
    const float4 b = xyz4[qB];
    const float tA = thr[qA];
    const float tB = thr[qB];

    for (int i = tid; i < 512; i += 256) tile[i] = xyz4[cbase + i];
    __syncthreads();

    int cntA = 0, cntB = 0;
#pragma unroll 8
    for (int j = 0; j < 512; ++j) {
        const float4 c = tile[j];
        const float eA = fmaf(-a.x, c.x, fmaf(-a.y, c.y, fmaf(-a.z, c.z, c.w)));
        const float eB = fmaf(-b.x, c.x, fmaf(-b.y, c.y, fmaf(-b.z, c.z, c.w)));
        if (eA < tA) {
            if (cntA < CAP) {
                dcomp[(size_t)(ch * CAP + cntA) * NTOT + qA] = eA;
                jcomp[(size_t)(ch * CAP + cntA) * NTOT + qA] = (u16)j;
            }
            ++cntA;
        }
        if (eB < tB) {
            if (cntB < CAP) {
                dcomp[(size_t)(ch * CAP + cntB) * NTOT + qB] = eB;
                jcomp[(size_t)(ch * CAP + cntB) * NTOT + qB] = (u16)j;
            }
            ++cntB;
        }
    }
    counts[(size_t)ch * NTOT + qA] = (u32)min(cntA, CAP);
    counts[(size_t)ch * NTOT + qB] = (u32)min(cntB, CAP);
}

// ---------------------------------------------------------------------------
// Kernel 4: merge survivor lists -> exact top-16 (validated insert semantics,
// chunk-major = global ascending scan order; strict < keeps earliest index).
// ---------------------------------------------------------------------------
__global__ __launch_bounds__(256) void knn_merge(const float* __restrict__ dcomp,
                                                 const u16* __restrict__ jcomp,
                                                 const u32* __restrict__ counts,
                                                 int* __restrict__ knn_out) {
    const int g = blockIdx.x * 256 + threadIdx.x;
    const int bbase = (g >> 13) * N_PTS;
    float dist[KNN];
    int idx[KNN];
#pragma unroll
    for (int s = 0; s < KNN; ++s) { dist[s] = 1e30f; idx[s] = 0; }

    for (int ch = 0; ch < NCH_S; ++ch) {
        const int cnt = (int)counts[(size_t)ch * NTOT + g];
        for (int t = 0; t < cnt; ++t) {
            const float d = dcomp[(size_t)(ch * CAP + t) * NTOT + g];
            const int j = (int)jcomp[(size_t)(ch * CAP + t) * NTOT + g];
            const int id = bbase + ch * 512 + j;
            if (d < dist[KNN - 1]) {
                dist[KNN - 1] = d;
                idx[KNN - 1] = id;
#pragma unroll
                for (int s = KNN - 1; s > 0; --s) {
                    if (dist[s] < dist[s - 1]) {
                        const float td = dist[s]; dist[s] = dist[s - 1]; dist[s - 1] = td;
                        const int ti = idx[s]; idx[s] = idx[s - 1]; idx[s - 1] = ti;
                    }
                }
            }
        }
    }
#pragma unroll
    for (int s = 0; s < KNN; ++s) knn_out[g * KNN + s] = idx[s];
}

// ---------------------------------------------------------------------------
// Kernel 5: q/k/v projections. q fp32; k,v bf16. (validated)
// ---------------------------------------------------------------------------
__global__ __launch_bounds__(256) void qkv_kernel(const float* __restrict__ feat,
                                                  const float* __restrict__ wq, const float* __restrict__ bq,
                                                  const float* __restrict__ wk, const float* __restrict__ bk,
                                                  const float* __restrict__ wv, const float* __restrict__ bv,
                                                  float* __restrict__ qbuf, u16* __restrict__ kb,
                                                  u16* __restrict__ vb) {
    __shared__ float ftile[64][D];
    const int r0 = blockIdx.x * 64;

    const float* src = feat + (size_t)r0 * D;
    for (int i = threadIdx.x; i < 64 * D / 4; i += 256) {
        ((float4*)&ftile[0][0])[i] = ((const float4*)src)[i];
    }
    __syncthreads();

    const int col = threadIdx.x & (D - 1);
    const int rbase = (threadIdx.x >> 7) * 32;

    float accq[32], acck[32], accv[32];
    const float bqv = bq[col], bkv = bk[col], bvv = bv[col];
#pragma unroll
    for (int r = 0; r < 32; ++r) { accq[r] = bqv; acck[r] = bkv; accv[r] = bvv; }

    for (int i = 0; i < D; i += 4) {
        const float wq0 = wq[(i + 0) * D + col], wq1 = wq[(i + 1) * D + col];
        const float wq2 = wq[(i + 2) * D + col], wq3 = wq[(i + 3) * D + col];
        const float wk0 = wk[(i + 0) * D + col], wk1 = wk[(i + 1) * D + col];
        const float wk2 = wk[(i + 2) * D + col], wk3 = wk[(i + 3) * D + col];
        const float wv0 = wv[(i + 0) * D + col], wv1 = wv[(i + 1) * D + col];
        const float wv2 = wv[(i + 2) * D + col], wv3 = wv[(i + 3) * D + col];
#pragma unroll
        for (int r = 0; r < 32; ++r) {
            const float4 f = *(const float4*)&ftile[rbase + r][i];
            accq[r] = fmaf(f.x, wq0, accq[r]); accq[r] = fmaf(f.y, wq1, accq[r]);
            accq[r] = fmaf(f.z, wq2, accq[r]); accq[r] = fmaf(f.w, wq3, accq[r]);
            acck[r] = fmaf(f.x, wk0, acck[r]); acck[r] = fmaf(f.y, wk1, acck[r]);
            acck[r] = fmaf(f.z, wk2, acck[r]); acck[r] = fmaf(f.w, wk3, acck[r]);
            accv[r] = fmaf(f.x, wv0, accv[r]); accv[r] = fmaf(f.y, wv1, accv[r]);
            accv[r] = fmaf(f.z, wv2, accv[r]); accv[r] = fmaf(f.w, wv3, accv[r]);
        }
    }
#pragma unroll
    for (int r = 0; r < 32; ++r) {
        const size_t o = (size_t)(r0 + rbase + r) * D + col;
        qbuf[o] = accq[r]; kb[o] = f2bf(acck[r]); vb[o] = f2bf(accv[r]);
    }
}

// ---------------------------------------------------------------------------
// Kernel 6: pack pw2/aw1/aw2 into bf16 B-fragment order. (validated)
// ---------------------------------------------------------------------------
__global__ __launch_bounds__(256) void pack_w(const float* __restrict__ pw2,
                                              const float* __restrict__ aw1,
                                              const float* __restrict__ aw2,
                                              u16* __restrict__ wp) {
    const int i = blockIdx.x * 256 + threadIdx.x;
    const int m = i >> 14;
    const int r = i & 16383;
    const int j = r & 7, l = (r >> 3) & 63, t = (r >> 9) & 7, q = r >> 12;
    const float* w = (m == 0) ? pw2 : (m == 1) ? aw1 : aw2;
    wp[i] = f2bf(w[(q * 32 + 8 * (l >> 4) + j) * D + t * 16 + (l & 15)]);
}

// ---------------------------------------------------------------------------
// Kernel 7: fused point transformer, GEMM-batched. (validated)
// ---------------------------------------------------------------------------
__device__ __forceinline__ void gemm_tile(const char* atile, const u16* wl, int mat,
                                          const float* brow, int a, int c2, int lane,
                                          f32x4 acc[2][2]) {
    const int c16 = lane & 15, grp = lane >> 4;
#pragma unroll
    for (int mt = 0; mt < 2; ++mt)
#pragma unroll
        for (int ct = 0; ct < 2; ++ct) {
            const float b = brow[c2 * 32 + ct * 16 + c16];
            acc[mt][ct] = (f32x4){b, b, b, b};
        }
#pragma unroll
    for (int q = 0; q < 4; ++q) {
        short8b af[2], bf[2];
#pragma unroll
        for (int mt = 0; mt < 2; ++mt) {
            const int row = (2 * a + mt) * 16 + c16;
            const int byte = (row * 256 + (q * 32 + grp * 8) * 2) ^ ((row & 7) << 4);
            af[mt] = *(const short8b*)(atile + byte);
        }
#pragma unroll
        for (int ct = 0; ct < 2; ++ct) {
            const int tg = c2 * 2 + ct;
            bf[ct] = *(const short8b*)((const char*)wl + (size_t)mat * 32768 +
                                       (size_t)((q * 8 + tg) * 64 + lane) * 16);
        }
#pragma unroll
        for (int mt = 0; mt < 2; ++mt)
#pragma unroll
            for (int ct = 0; ct < 2; ++ct)
                acc[mt][ct] = __builtin_amdgcn_mfma_f32_16x16x32_bf16(af[mt], bf[ct], acc[mt][ct], 0, 0, 0);
    }
}

__global__ __launch_bounds__(1024, 4) void fused_v3(const float* __restrict__ xyz,
                                                    const float* __restrict__ qbuf,
                                                    const u16* __restrict__ kb,
                                                    const u16* __restrict__ vb,
                                                    const int* __restrict__ knn_in,
                                                    const u16* __restrict__ wpack,
                                                    const float* __restrict__ pw1,
                                                    const float* __restrict__ pb1,
                                                    const float* __restrict__ pb2,
                                                    const float* __restrict__ ab1,
                                                    const float* __restrict__ ab2,
                                                    float* __restrict__ out) {
    __shared__ __align__(16) u16 wlds[49152];     // 96 KB: pw2, aw1, aw2
    __shared__ __align__(16) char atile[32768];   // [128][128] bf16 swizzled
    __shared__ float pw1s[3][D];
    __shared__ float pb1s[D];
    __shared__ float bias[3][D];                  // pb2, ab1, ab2
    __shared__ float diffs[128][4];
    __shared__ int nbrs[128];

    const int tid = threadIdx.x;
    {
        const uint4* s = (const uint4*)wpack;
        uint4* d = (uint4*)wlds;
        for (int i = tid; i < 6144; i += 1024) d[i] = s[i];
        if (tid < 384) pw1s[tid >> 7][tid & 127] = pw1[tid];
        if (tid < 128) pb1s[tid] = pb1[tid];
        else if (tid < 256) bias[0][tid & 127] = pb2[tid & 127];
        else if (tid < 512 && tid >= 384) bias[1][tid & 127] = ab1[tid & 127];
        else if (tid >= 512 && tid < 640) bias[2][tid & 127] = ab2[tid & 127];
    }

    const int wid = tid >> 6, lane = tid & 63;
    const int a = wid >> 2, c2 = wid & 3;
    const int c16 = lane & 15, grp = lane >> 4;

    for (int g = 0; g < 8; ++g) {
        const int p0 = blockIdx.x * 64 + g * 8;
        __syncthreads();   // protects atile/nbrs/diffs from previous group

        // P1: neighbor ids + pos diffs
        if (tid < 128) {
            const int pt = p0 + (tid >> 4);
            const int nb = knn_in[pt * KNN + (tid & 15)];
            nbrs[tid] = nb;
            diffs[tid][0] = xyz[pt * 3 + 0] - xyz[nb * 3 + 0];
            diffs[tid][1] = xyz[pt * 3 + 1] - xyz[nb * 3 + 1];
            diffs[tid][2] = xyz[pt * 3 + 2] - xyz[nb * 3 + 2];
        }
        __syncthreads();

        // P2: h1 = relu(pos_diff @ pw1 + pb1) -> atile (VALU, K=3)
        {
            const int row = tid >> 3;
            const int c0 = (tid & 7) * 16;
            const float d0 = diffs[row][0], d1 = diffs[row][1], d2 = diffs[row][2];
#pragma unroll
            for (int c = 0; c < 16; c += 2) {
                const int cc = c0 + c;
                float h0 = pb1s[cc];
                h0 = fmaf(d0, pw1s[0][cc], h0); h0 = fmaf(d1, pw1s[1][cc], h0); h0 = fmaf(d2, pw1s[2][cc], h0);
                float h1 = pb1s[cc + 1];
                h1 = fmaf(d0, pw1s[0][cc + 1], h1); h1 = fmaf(d1, pw1s[1][cc + 1], h1); h1 = fmaf(d2, pw1s[2][cc + 1], h1);
                const u32 packed = (u32)f2bf(fmaxf(h0, 0.f)) | ((u32)f2bf(fmaxf(h1, 0.f)) << 16);
                const int byte = (row * 256 + cc * 2) ^ ((row & 7) << 4);
                *(u32*)(atile + byte) = packed;
            }
        }
        __syncthreads();

        // P3: delta = h1 @ pw2 + pb2 (regs, C-layout)
        f32x4 del[2][2];
        gemm_tile(atile, wlds, 0, bias[0], a, c2, lane, del);
        __syncthreads();   // all A-reads done

        // P4: attn_in = q - k_g + delta -> atile
#pragma unroll
        for (int mt = 0; mt < 2; ++mt) {
            const int pt = p0 + 2 * a + mt;
#pragma unroll
            for (int ct = 0; ct < 2; ++ct) {
                const int col = c2 * 32 + ct * 16 + c16;
                const float qv = qbuf[(size_t)pt * D + col];
#pragma unroll
                for (int r = 0; r < 4; ++r) {
                    const int lrow = (2 * a + mt) * 16 + grp * 4 + r;
                    const int nb = nbrs[lrow];
                    const float kg = bf2f(kb[(size_t)nb * D + col]);
                    const float v = qv - kg + del[mt][ct][r];
                    const int byte = (lrow * 256 + col * 2) ^ ((lrow & 7) << 4);
                    *(u16*)(atile + byte) = f2bf(v);
                }
            }
        }
        __syncthreads();

        // P5: h2 = relu(attn_in @ aw1 + ab1)
        f32x4 acc[2][2];
        gemm_tile(atile, wlds, 1, bias[1], a, c2, lane, acc);
        __syncthreads();   // all A-reads done

        // P6: store relu(h2) -> atile
#pragma unroll
        for (int mt = 0; mt < 2; ++mt)
#pragma unroll
            for (int ct = 0; ct < 2; ++ct) {
                const int col = c2 * 32 + ct * 16 + c16;
#pragma unroll
                for (int r = 0; r < 4; ++r) {
                    const int lrow = (2 * a + mt) * 16 + grp * 4 + r;
                    const int byte = (lrow * 256 + col * 2) ^ ((lrow & 7) << 4);
                    *(u16*)(atile + byte) = f2bf(fmaxf(acc[mt][ct][r], 0.f));
                }
            }
        __syncthreads();

        // P7: logits = h2 @ aw2 + ab2
        gemm_tile(atile, wlds, 2, bias[2], a, c2, lane, acc);

        // P8: softmax over 16 neighbors (rows of M-tile) + weighted sum
        float om[2][2];
#pragma unroll
        for (int mt = 0; mt < 2; ++mt) {
#pragma unroll
            for (int ct = 0; ct < 2; ++ct) {
                const int col = c2 * 32 + ct * 16 + c16;
                // prefetch v_g
                float vg[4];
#pragma unroll
                for (int r = 0; r < 4; ++r) {
                    const int lrow = (2 * a + mt) * 16 + grp * 4 + r;
                    vg[r] = bf2f(vb[(size_t)nbrs[lrow] * D + col]);
                }
                float m = fmaxf(fmaxf(acc[mt][ct][0], acc[mt][ct][1]),
                                fmaxf(acc[mt][ct][2], acc[mt][ct][3]));
                m = fmaxf(m, __shfl_xor(m, 16));
                m = fmaxf(m, __shfl_xor(m, 32));
                float e[4], s = 0.f;
#pragma unroll
                for (int r = 0; r < 4; ++r) { e[r] = __expf(acc[mt][ct][r] - m); s += e[r]; }
                s += __shfl_xor(s, 16);
                s += __shfl_xor(s, 32);
                const float inv = 1.f / s;
                float o = 0.f;
#pragma unroll
                for (int r = 0; r < 4; ++r) o = fmaf(e[r] * inv, vg[r] + del[mt][ct][r], o);
                o += __shfl_xor(o, 16);
                o += __shfl_xor(o, 32);
                om[mt][ct] = o;
            }
        }
        float osel = om[0][0];
        if (grp == 1) osel = om[0][1];
        if (grp == 2) osel = om[1][0];
        if (grp == 3) osel = om[1][1];
        const int opt = p0 + 2 * a + (grp >> 1);
        out[(size_t)opt * D + c2 * 32 + (grp & 1) * 16 + c16] = osel;
    }
}

// ---------------------------------------------------------------------------
extern "C" void kernel_launch(void* const* d_in, const int* in_sizes, int n_in,
                              void* d_out, int out_size, void* d_ws, size_t ws_size,
                              hipStream_t stream) {
    const float* xyz = (const float*)d_in[0];
    const float* feat = (const float*)d_in[1];
    const float* wq = (const float*)d_in[2];
    const float* bq = (const float*)d_in[3];
    const float* wk = (const float*)d_in[4];
    const float* bk = (const float*)d_in[5];
    const float* wv = (const float*)d_in[6];
    const float* bv = (const float*)d_in[7];
    const float* pw1 = (const float*)d_in[8];
    const float* pb1 = (const float*)d_in[9];
    const float* pw2 = (const float*)d_in[10];
    const float* pb2 = (const float*)d_in[11];
    const float* aw1 = (const float*)d_in[12];
    const float* ab1 = (const float*)d_in[13];
    const float* aw2 = (const float*)d_in[14];
    const float* ab2 = (const float*)d_in[15];

    float* ws = (float*)d_ws;
    // --- knn phase ---
    // dcomp [16ch][20cap][16384] f32 = 5,242,880 f32; pmins overlays its head
    float* dcomp = ws;                              // also pmins [128][16384]
    float* pmins = ws;
    u16* jcomp = (u16*)(ws + 5242880);              // 5,242,880 u16 (2,621,440 f32)
    u32* counts = (u32*)(ws + 7864320);             // 262,144 u32
    float* thr = ws + 8126464;                      // 16,384 f32
    int* knn = (int*)(ws + 8142848);                // 262,144 i32
    float4* xyz4 = (float4*)(ws + 8404992);         // 16,384 float4 (65,536 f32)
    // --- mlp phase (overlays dcomp region, dead after merge) ---
    float* qbuf = ws;                               // 2,097,152 f32
    u16* kb = (u16*)(ws + 2097152);                 // 2,097,152 u16
    u16* vb = (u16*)(ws + 3145728);                 // 2,097,152 u16
    u16* wpack = (u16*)(ws + 4194304);              // 49,152 u16
    float* out = (float*)d_out;

    hipLaunchKernelGGL(xyz4_prep, dim3(64), dim3(256), 0, stream, xyz, xyz4);
    hipLaunchKernelGGL(knn_minslots, dim3(64, NCH_M), dim3(128), 0, stream, xyz4, pmins);
    hipLaunchKernelGGL(knn_thresh, dim3(64), dim3(256), 0, stream, pmins, thr);
    hipLaunchKernelGGL(knn_select, dim3(32, NCH_S), dim3(256), 0, stream,
                       xyz4, thr, dcomp, jcomp, counts);
    hipLaunchKernelGGL(knn_merge, dim3(64), dim3(256), 0, stream, dcomp, jcomp, counts, knn);
    hipLaunchKernelGGL(qkv_kernel, dim3(256), dim3(256), 0, stream,
                       feat, wq, bq, wk, bk, wv, bv, qbuf, kb, vb);
    hipLaunchKernelGGL(pack_w, dim3(192), dim3(256), 0, stream, pw2, aw1, aw2, wpack);
    hipLaunchKernelGGL(fused_v3, dim3(256), dim3(1024), 0, stream,
                       xyz, qbuf, kb, vb, knn, wpack,
                       pw1, pb1, pb2, ab1, ab2, out);
}

// Round 5
// 316.107 us; speedup vs baseline: 3.4032x; 1.2919x over previous
//
#include <hip/hip_runtime.h>
#include <math.h>

typedef unsigned short u16;
typedef unsigned int u32;
typedef __attribute__((ext_vector_type(8))) short short8b;  // 8 x bf16
typedef __attribute__((ext_vector_type(4))) float f32x4;

#define N_PTS 8192
#define NTOT 16384
#define D 128
#define KNN 16
#define NCH_M 8            // minslots chunks (1024 cands)
#define NCH_S 16           // select chunks (512 cands)
#define CAP 20             // survivor cap per (query, select-chunk)

__device__ __forceinline__ u16 f2bf(float x) {
    u32 u = __float_as_uint(x);
    u = (u + 0x7FFFu + ((u >> 16) & 1u)) >> 16;
    return (u16)u;
}
__device__ __forceinline__ float bf2f(u16 v) {
    return __uint_as_float(((u32)v) << 16);
}

// ---------------------------------------------------------------------------
// Kernel 0: xyz4[i] = (x, y, z, 0.5*|p|^2)  — coalesced candidate table.
// ---------------------------------------------------------------------------
__global__ __launch_bounds__(256) void xyz4_prep(const float* __restrict__ xyz,
                                                 float4* __restrict__ xyz4) {
    const int i = blockIdx.x * 256 + threadIdx.x;
    const float x = xyz[i * 3 + 0], y = xyz[i * 3 + 1], z = xyz[i * 3 + 2];
    xyz4[i] = make_float4(x, y, z, 0.5f * (x * x + y * y + z * z));
}

// ---------------------------------------------------------------------------
// Kernel 1: residue-min slots in e-space. grid (64, 8), block 128, 2 q/thread.
// e = 0.5|c|^2 - q.c  (strictly monotone in squared distance per query).
// ---------------------------------------------------------------------------
__global__ __launch_bounds__(128) void knn_minslots(const float4* __restrict__ xyz4,
                                                    float* __restrict__ pmins) {
    __shared__ float4 tile[1024];   // 16 KB
    const int tid = threadIdx.x;
    const int qA = blockIdx.x * 256 + tid;
    const int qB = qA + 128;
    const int cbase = (qA >> 13) * N_PTS + blockIdx.y * 1024;

    const float4 a = xyz4[qA];
    const float4 b = xyz4[qB];

    for (int i = tid; i < 1024; i += 128) tile[i] = xyz4[cbase + i];
    __syncthreads();

    float sA[16], sB[16];
#pragma unroll
    for (int s = 0; s < 16; ++s) { sA[s] = 1e30f; sB[s] = 1e30f; }

    for (int j0 = 0; j0 < 1024; j0 += 16) {
#pragma unroll
        for (int s = 0; s < 16; ++s) {
            const float4 c = tile[j0 + s];
            const float eA = fmaf(-a.x, c.x, fmaf(-a.y, c.y, fmaf(-a.z, c.z, c.w)));
            const float eB = fmaf(-b.x, c.x, fmaf(-b.y, c.y, fmaf(-b.z, c.z, c.w)));
            sA[s] = fminf(sA[s], eA);
            sB[s] = fminf(sB[s], eB);
        }
    }
#pragma unroll
    for (int s = 0; s < 16; ++s) {
        pmins[(size_t)(blockIdx.y * 16 + s) * NTOT + qA] = sA[s];
        pmins[(size_t)(blockIdx.y * 16 + s) * NTOT + qB] = sB[s];
    }
}

// ---------------------------------------------------------------------------
// Kernel 2: T'[g] = nextup(max_s min_chunks slots) — safe threshold (> e16).
// ---------------------------------------------------------------------------
__global__ __launch_bounds__(256) void knn_thresh(const float* __restrict__ pmins,
                                                  float* __restrict__ thr) {
    const int g = blockIdx.x * 256 + threadIdx.x;
    float m[16];
#pragma unroll
    for (int s = 0; s < 16; ++s) m[s] = 1e30f;
    for (int ch = 0; ch < NCH_M; ++ch) {
#pragma unroll
        for (int s = 0; s < 16; ++s)
            m[s] = fminf(m[s], pmins[(size_t)(ch * 16 + s) * NTOT + g]);
    }
    float T = m[0];
#pragma unroll
    for (int s = 1; s < 16; ++s) T = fmaxf(T, m[s]);
    u32 u = __float_as_uint(T);
    u = (T >= 0.f) ? (u + 1u) : (u - 1u);   // nextafter toward +inf
    thr[g] = __uint_as_float(u);
}

// ---------------------------------------------------------------------------
// Kernel 3: filter-and-append selection. grid (32, 16), block 256, 2 q/thread.
// Appends (e, local j) of survivors (e < T'); pads unused slots with 1e30
// sentinels so the merge runs a fixed trip count with no counts array.
// ---------------------------------------------------------------------------
__global__ __launch_bounds__(256) void knn_select(const float4* __restrict__ xyz4,
                                                  const float* __restrict__ thr,
                                                  float* __restrict__ dcomp,
                                                  u16* __restrict__ jcomp) {
    __shared__ float4 tile[512];   // 8 KB
    const int tid = threadIdx.x;
    const int ch = blockIdx.y;
    const int qA = blockIdx.x * 512 + tid;
    const int qB = qA + 256;
    const int cbase = (qA >> 13) * N_PTS + ch * 512;

    const float4 a = xyz4[qA];
    const float4 b = xyz4[qB];
    const float tA = thr[qA];
    const float tB = thr[qB];

    for (int i = tid; i < 512; i += 256) tile[i] = xyz4[cbase + i];
    __syncthreads();

    int cntA = 0, cntB = 0;
#pragma unroll 8
    for (int j = 0; j < 512; ++j) {
        const float4 c = tile[j];
        const float eA = fmaf(-a.x, c.x, fmaf(-a.y, c.y, fmaf(-a.z, c.z, c.w)));
        const float eB = fmaf(-b.x, c.x, fmaf(-b.y, c.y, fmaf(-b.z, c.z, c.w)));
        if (eA < tA) {
            if (cntA < CAP) {
                dcomp[(size_t)(ch * CAP + cntA) * NTOT + qA] = eA;
                jcomp[(size_t)(ch * CAP + cntA) * NTOT + qA] = (u16)j;
            }
            ++cntA;
        }
        if (eB < tB) {
            if (cntB < CAP) {
                dcomp[(size_t)(ch * CAP + cntB) * NTOT + qB] = eB;
                jcomp[(size_t)(ch * CAP + cntB) * NTOT + qB] = (u16)j;
            }
            ++cntB;
        }
    }
    // pad remaining slots with sentinels (never insert in merge)
    for (int t = min(cntA, CAP); t < CAP; ++t)
        dcomp[(size_t)(ch * CAP + t) * NTOT + qA] = 1e30f;
    for (int t = min(cntB, CAP); t < CAP; ++t)
        dcomp[(size_t)(ch * CAP + t) * NTOT + qB] = 1e30f;
}

// ---------------------------------------------------------------------------
// Kernel 4: merge survivor lists -> exact top-16. Fixed trip count: inner
// CAP-loop fully unrolled (40 coalesced loads batched per chunk iteration);
// sentinel 1e30 entries never trigger. Scan order (chunk-major, t ascending,
// strict <) identical to validated semantics. grid 256 x block 64.
// ---------------------------------------------------------------------------
__global__ __launch_bounds__(64) void knn_merge(const float* __restrict__ dcomp,
                                                const u16* __restrict__ jcomp,
                                                int* __restrict__ knn_out) {
    const int g = blockIdx.x * 64 + threadIdx.x;
    const int bbase = (g >> 13) * N_PTS;
    float dist[KNN];
    int idx[KNN];
#pragma unroll
    for (int s = 0; s < KNN; ++s) { dist[s] = 1e30f; idx[s] = 0; }

    for (int ch = 0; ch < NCH_S; ++ch) {
        float d[CAP];
        int jj[CAP];
#pragma unroll
        for (int t = 0; t < CAP; ++t) {
            d[t] = dcomp[(size_t)(ch * CAP + t) * NTOT + g];
            jj[t] = (int)jcomp[(size_t)(ch * CAP + t) * NTOT + g];
        }
#pragma unroll
        for (int t = 0; t < CAP; ++t) {
            if (d[t] < dist[KNN - 1]) {
                dist[KNN - 1] = d[t];
                idx[KNN - 1] = bbase + ch * 512 + jj[t];
#pragma unroll
                for (int s = KNN - 1; s > 0; --s) {
                    if (dist[s] < dist[s - 1]) {
                        const float td = dist[s]; dist[s] = dist[s - 1]; dist[s - 1] = td;
                        const int ti = idx[s]; idx[s] = idx[s - 1]; idx[s - 1] = ti;
                    }
                }
            }
        }
    }
#pragma unroll
    for (int s = 0; s < KNN; ++s) knn_out[g * KNN + s] = idx[s];
}

// ---------------------------------------------------------------------------
// Kernel 5: q/k/v projections. q fp32; k,v bf16. (validated)
// ---------------------------------------------------------------------------
__global__ __launch_bounds__(256) void qkv_kernel(const float* __restrict__ feat,
                                                  const float* __restrict__ wq, const float* __restrict__ bq,
                                                  const float* __restrict__ wk, const float* __restrict__ bk,
                                                  const float* __restrict__ wv, const float* __restrict__ bv,
                                                  float* __restrict__ qbuf, u16* __restrict__ kb,
                                                  u16* __restrict__ vb) {
    __shared__ float ftile[64][D];
    const int r0 = blockIdx.x * 64;

    const float* src = feat + (size_t)r0 * D;
    for (int i = threadIdx.x; i < 64 * D / 4; i += 256) {
        ((float4*)&ftile[0][0])[i] = ((const float4*)src)[i];
    }
    __syncthreads();

    const int col = threadIdx.x & (D - 1);
    const int rbase = (threadIdx.x >> 7) * 32;

    float accq[32], acck[32], accv[32];
    const float bqv = bq[col], bkv = bk[col], bvv = bv[col];
#pragma unroll
    for (int r = 0; r < 32; ++r) { accq[r] = bqv; acck[r] = bkv; accv[r] = bvv; }

    for (int i = 0; i < D; i += 4) {
        const float wq0 = wq[(i + 0) * D + col], wq1 = wq[(i + 1) * D + col];
        const float wq2 = wq[(i + 2) * D + col], wq3 = wq[(i + 3) * D + col];
        const float wk0 = wk[(i + 0) * D + col], wk1 = wk[(i + 1) * D + col];
        const float wk2 = wk[(i + 2) * D + col], wk3 = wk[(i + 3) * D + col];
        const float wv0 = wv[(i + 0) * D + col], wv1 = wv[(i + 1) * D + col];
        const float wv2 = wv[(i + 2) * D + col], wv3 = wv[(i + 3) * D + col];
#pragma unroll
        for (int r = 0; r < 32; ++r) {
            const float4 f = *(const float4*)&ftile[rbase + r][i];
            accq[r] = fmaf(f.x, wq0, accq[r]); accq[r] = fmaf(f.y, wq1, accq[r]);
            accq[r] = fmaf(f.z, wq2, accq[r]); accq[r] = fmaf(f.w, wq3, accq[r]);
            acck[r] = fmaf(f.x, wk0, acck[r]); acck[r] = fmaf(f.y, wk1, acck[r]);
            acck[r] = fmaf(f.z, wk2, acck[r]); acck[r] = fmaf(f.w, wk3, acck[r]);
            accv[r] = fmaf(f.x, wv0, accv[r]); accv[r] = fmaf(f.y, wv1, accv[r]);
            accv[r] = fmaf(f.z, wv2, accv[r]); accv[r] = fmaf(f.w, wv3, accv[r]);
        }
    }
#pragma unroll
    for (int r = 0; r < 32; ++r) {
        const size_t o = (size_t)(r0 + rbase + r) * D + col;
        qbuf[o] = accq[r]; kb[o] = f2bf(acck[r]); vb[o] = f2bf(accv[r]);
    }
}

// ---------------------------------------------------------------------------
// Kernel 6: pack pw2/aw1/aw2 into bf16 B-fragment order. (validated)
// ---------------------------------------------------------------------------
__global__ __launch_bounds__(256) void pack_w(const float* __restrict__ pw2,
                                              const float* __restrict__ aw1,
                                              const float* __restrict__ aw2,
                                              u16* __restrict__ wp) {
    const int i = blockIdx.x * 256 + threadIdx.x;
    const int m = i >> 14;
    const int r = i & 16383;
    const int j = r & 7, l = (r >> 3) & 63, t = (r >> 9) & 7, q = r >> 12;
    const float* w = (m == 0) ? pw2 : (m == 1) ? aw1 : aw2;
    wp[i] = f2bf(w[(q * 32 + 8 * (l >> 4) + j) * D + t * 16 + (l & 15)]);
}

// ---------------------------------------------------------------------------
// Kernel 7: fused point transformer, GEMM-batched. (validated)
// ---------------------------------------------------------------------------
__device__ __forceinline__ void gemm_tile(const char* atile, const u16* wl, int mat,
                                          const float* brow, int a, int c2, int lane,
                                          f32x4 acc[2][2]) {
    const int c16 = lane & 15, grp = lane >> 4;
#pragma unroll
    for (int mt = 0; mt < 2; ++mt)
#pragma unroll
        for (int ct = 0; ct < 2; ++ct) {
            const float b = brow[c2 * 32 + ct * 16 + c16];
            acc[mt][ct] = (f32x4){b, b, b, b};
        }
#pragma unroll
    for (int q = 0; q < 4; ++q) {
        short8b af[2], bf[2];
#pragma unroll
        for (int mt = 0; mt < 2; ++mt) {
            const int row = (2 * a + mt) * 16 + c16;
            const int byte = (row * 256 + (q * 32 + grp * 8) * 2) ^ ((row & 7) << 4);
            af[mt] = *(const short8b*)(atile + byte);
        }
#pragma unroll
        for (int ct = 0; ct < 2; ++ct) {
            const int tg = c2 * 2 + ct;
            bf[ct] = *(const short8b*)((const char*)wl + (size_t)mat * 32768 +
                                       (size_t)((q * 8 + tg) * 64 + lane) * 16);
        }
#pragma unroll
        for (int mt = 0; mt < 2; ++mt)
#pragma unroll
            for (int ct = 0; ct < 2; ++ct)
                acc[mt][ct] = __builtin_amdgcn_mfma_f32_16x16x32_bf16(af[mt], bf[ct], acc[mt][ct], 0, 0, 0);
    }
}

__global__ __launch_bounds__(1024, 4) void fused_v3(const float* __restrict__ xyz,
                                                    const float* __restrict__ qbuf,
                                                    const u16* __restrict__ kb,
                                                    const u16* __restrict__ vb,
                                                    const int* __restrict__ knn_in,
                                                    const u16* __restrict__ wpack,
                                                    const float* __restrict__ pw1,
                                                    const float* __restrict__ pb1,
                                                    const float* __restrict__ pb2,
                                                    const float* __restrict__ ab1,
                                                    const float* __restrict__ ab2,
                                                    float* __restrict__ out) {
    __shared__ __align__(16) u16 wlds[49152];     // 96 KB: pw2, aw1, aw2
    __shared__ __align__(16) char atile[32768];   // [128][128] bf16 swizzled
    __shared__ float pw1s[3][D];
    __shared__ float pb1s[D];
    __shared__ float bias[3][D];                  // pb2, ab1, ab2
    __shared__ float diffs[128][4];
    __shared__ int nbrs[128];

    const int tid = threadIdx.x;
    {
        const uint4* s = (const uint4*)wpack;
        uint4* d = (uint4*)wlds;
        for (int i = tid; i < 6144; i += 1024) d[i] = s[i];
        if (tid < 384) pw1s[tid >> 7][tid & 127] = pw1[tid];
        if (tid < 128) pb1s[tid] = pb1[tid];
        else if (tid < 256) bias[0][tid & 127] = pb2[tid & 127];
        else if (tid < 512 && tid >= 384) bias[1][tid & 127] = ab1[tid & 127];
        else if (tid >= 512 && tid < 640) bias[2][tid & 127] = ab2[tid & 127];
    }

    const int wid = tid >> 6, lane = tid & 63;
    const int a = wid >> 2, c2 = wid & 3;
    const int c16 = lane & 15, grp = lane >> 4;

    for (int g = 0; g < 8; ++g) {
        const int p0 = blockIdx.x * 64 + g * 8;
        __syncthreads();   // protects atile/nbrs/diffs from previous group

        // P1: neighbor ids + pos diffs
        if (tid < 128) {
            const int pt = p0 + (tid >> 4);
            const int nb = knn_in[pt * KNN + (tid & 15)];
            nbrs[tid] = nb;
            diffs[tid][0] = xyz[pt * 3 + 0] - xyz[nb * 3 + 0];
            diffs[tid][1] = xyz[pt * 3 + 1] - xyz[nb * 3 + 1];
            diffs[tid][2] = xyz[pt * 3 + 2] - xyz[nb * 3 + 2];
        }
        __syncthreads();

        // P2: h1 = relu(pos_diff @ pw1 + pb1) -> atile (VALU, K=3)
        {
            const int row = tid >> 3;
            const int c0 = (tid & 7) * 16;
            const float d0 = diffs[row][0], d1 = diffs[row][1], d2 = diffs[row][2];
#pragma unroll
            for (int c = 0; c < 16; c += 2) {
                const int cc = c0 + c;
                float h0 = pb1s[cc];
                h0 = fmaf(d0, pw1s[0][cc], h0); h0 = fmaf(d1, pw1s[1][cc], h0); h0 = fmaf(d2, pw1s[2][cc], h0);
                float h1 = pb1s[cc + 1];
                h1 = fmaf(d0, pw1s[0][cc + 1], h1); h1 = fmaf(d1, pw1s[1][cc + 1], h1); h1 = fmaf(d2, pw1s[2][cc + 1], h1);
                const u32 packed = (u32)f2bf(fmaxf(h0, 0.f)) | ((u32)f2bf(fmaxf(h1, 0.f)) << 16);
                const int byte = (row * 256 + cc * 2) ^ ((row & 7) << 4);
                *(u32*)(atile + byte) = packed;
            }
        }
        __syncthreads();

        // P3: delta = h1 @ pw2 + pb2 (regs, C-layout)
        f32x4 del[2][2];
        gemm_tile(atile, wlds, 0, bias[0], a, c2, lane, del);
        __syncthreads();   // all A-reads done

        // P4: attn_in = q - k_g + delta -> atile
#pragma unroll
        for (int mt = 0; mt < 2; ++mt) {
            const int pt = p0 + 2 * a + mt;
#pragma unroll
            for (int ct = 0; ct < 2; ++ct) {
                const int col = c2 * 32 + ct * 16 + c16;
                const float qv = qbuf[(size_t)pt * D + col];
#pragma unroll
                for (int r = 0; r < 4; ++r) {
                    const int lrow = (2 * a + mt) * 16 + grp * 4 + r;
                    const int nb = nbrs[lrow];
                    const float kg = bf2f(kb[(size_t)nb * D + col]);
                    const float v = qv - kg + del[mt][ct][r];
                    const int byte = (lrow * 256 + col * 2) ^ ((lrow & 7) << 4);
                    *(u16*)(atile + byte) = f2bf(v);
                }
            }
        }
        __syncthreads();

        // P5: h2 = relu(attn_in @ aw1 + ab1)
        f32x4 acc[2][2];
        gemm_tile(atile, wlds, 1, bias[1], a, c2, lane, acc);
        __syncthreads();   // all A-reads done

        // P6: store relu(h2) -> atile
#pragma unroll
        for (int mt = 0; mt < 2; ++mt)
#pragma unroll
            for (int ct = 0; ct < 2; ++ct) {
                const int col = c2 * 32 + ct * 16 + c16;
#pragma unroll
                for (int r = 0; r < 4; ++r) {
                    const int lrow = (2 * a + mt) * 16 + grp * 4 + r;
                    const int byte = (lrow * 256 + col * 2) ^ ((lrow & 7) << 4);
                    *(u16*)(atile + byte) = f2bf(fmaxf(acc[mt][ct][r], 0.f));
                }
            }
        __syncthreads();

        // P7: logits = h2 @ aw2 + ab2
        gemm_tile(atile, wlds, 2, bias[2], a, c2, lane, acc);

        // P8: softmax over 16 neighbors (rows of M-tile) + weighted sum
        float om[2][2];
#pragma unroll
        for (int mt = 0; mt < 2; ++mt) {
#pragma unroll
            for (int ct = 0; ct < 2; ++ct) {
                const int col = c2 * 32 + ct * 16 + c16;
                // prefetch v_g
                float vg[4];
#pragma unroll
                for (int r = 0; r < 4; ++r) {
                    const int lrow = (2 * a + mt) * 16 + grp * 4 + r;
                    vg[r] = bf2f(vb[(size_t)nbrs[lrow] * D + col]);
                }
                float m = fmaxf(fmaxf(acc[mt][ct][0], acc[mt][ct][1]),
                                fmaxf(acc[mt][ct][2], acc[mt][ct][3]));
                m = fmaxf(m, __shfl_xor(m, 16));
                m = fmaxf(m, __shfl_xor(m, 32));
                float e[4], s = 0.f;
#pragma unroll
                for (int r = 0; r < 4; ++r) { e[r] = __expf(acc[mt][ct][r] - m); s += e[r]; }
                s += __shfl_xor(s, 16);
                s += __shfl_xor(s, 32);
                const float inv = 1.f / s;
                float o = 0.f;
#pragma unroll
                for (int r = 0; r < 4; ++r) o = fmaf(e[r] * inv, vg[r] + del[mt][ct][r], o);
                o += __shfl_xor(o, 16);
                o += __shfl_xor(o, 32);
                om[mt][ct] = o;
            }
        }
        float osel = om[0][0];
        if (grp == 1) osel = om[0][1];
        if (grp == 2) osel = om[1][0];
        if (grp == 3) osel = om[1][1];
        const int opt = p0 + 2 * a + (grp >> 1);
        out[(size_t)opt * D + c2 * 32 + (grp & 1) * 16 + c16] = osel;
    }
}

// ---------------------------------------------------------------------------
extern "C" void kernel_launch(void* const* d_in, const int* in_sizes, int n_in,
                              void* d_out, int out_size, void* d_ws, size_t ws_size,
                              hipStream_t stream) {
    const float* xyz = (const float*)d_in[0];
    const float* feat = (const float*)d_in[1];
    const float* wq = (const float*)d_in[2];
    const float* bq = (const float*)d_in[3];
    const float* wk = (const float*)d_in[4];
    const float* bk = (const float*)d_in[5];
    const float* wv = (const float*)d_in[6];
    const float* bv = (const float*)d_in[7];
    const float* pw1 = (const float*)d_in[8];
    const float* pb1 = (const float*)d_in[9];
    const float* pw2 = (const float*)d_in[10];
    const float* pb2 = (const float*)d_in[11];
    const float* aw1 = (const float*)d_in[12];
    const float* ab1 = (const float*)d_in[13];
    const float* aw2 = (const float*)d_in[14];
    const float* ab2 = (const float*)d_in[15];

    float* ws = (float*)d_ws;
    // --- knn phase ---
    // dcomp [16ch][20cap][16384] f32 = 5,242,880 f32; pmins overlays its head
    float* dcomp = ws;                              // also pmins [128][16384]
    float* pmins = ws;
    u16* jcomp = (u16*)(ws + 5242880);              // 5,242,880 u16 (2,621,440 f32)
    float* thr = ws + 8126464;                      // 16,384 f32
    int* knn = (int*)(ws + 8142848);                // 262,144 i32
    float4* xyz4 = (float4*)(ws + 8404992);         // 16,384 float4 (65,536 f32)
    // --- mlp phase (overlays dcomp region, dead after merge) ---
    float* qbuf = ws;                               // 2,097,152 f32
    u16* kb = (u16*)(ws + 2097152);                 // 2,097,152 u16
    u16* vb = (u16*)(ws + 3145728);                 // 2,097,152 u16
    u16* wpack = (u16*)(ws + 4194304);              // 49,152 u16
    float* out = (float*)d_out;

    hipLaunchKernelGGL(xyz4_prep, dim3(64), dim3(256), 0, stream, xyz, xyz4);
    hipLaunchKernelGGL(knn_minslots, dim3(64, NCH_M), dim3(128), 0, stream, xyz4, pmins);
    hipLaunchKernelGGL(knn_thresh, dim3(64), dim3(256), 0, stream, pmins, thr);
    hipLaunchKernelGGL(knn_select, dim3(32, NCH_S), dim3(256), 0, stream,
                       xyz4, thr, dcomp, jcomp);
    hipLaunchKernelGGL(knn_merge, dim3(256), dim3(64), 0, stream, dcomp, jcomp, knn);
    hipLaunchKernelGGL(qkv_kernel, dim3(256), dim3(256), 0, stream,
                       feat, wq, bq, wk, bk, wv, bv, qbuf, kb, vb);
    hipLaunchKernelGGL(pack_w, dim3(192), dim3(256), 0, stream, pw2, aw1, aw2, wpack);
    hipLaunchKernelGGL(fused_v3, dim3(256), dim3(1024), 0, stream,
                       xyz, qbuf, kb, vb, knn, wpack,
                       pw1, pb1, pb2, ab1, ab2, out);
}